// Round 11
// baseline (1257.829 us; speedup 1.0000x reference)
//
#include <hip/hip_runtime.h>

#define NB  8
#define NPT 4096
#define NS  1024
#define NK  32
#define DIN 6
#define QPB 32          // queries per mega-block
#define MEGA_THREADS 512

// mega LDS float offsets
#define OFF_A   0            // 131*128 = 16768
#define OFF_W1  16768        // 64*64   = 4096
#define OFF_W2  20864        // 128*64  = 8192
#define OFF_W0  29056        // 64*9    = 576
#define OFF_H1  29632        // 32*68   = 2176
#define OFF_H2  31808        // 32*68   = 2176
#define OFF_U   33984        // 32*132  = 4224
#define FLT_TOT 38208
#define SMEM_BYTES (FLT_TOT * 4)   // 152832 B <= 160 KiB

// ---------------------------------------------------------------------------
__device__ __forceinline__ float bnrelu(float acc, const float* __restrict__ bb,
                                        const float* __restrict__ gg,
                                        const float* __restrict__ be,
                                        const float* __restrict__ mm,
                                        const float* __restrict__ vv, int oc) {
  float t = (acc + bb[oc]) - mm[oc];
  float val = gg[oc] * t * rsqrtf(vv[oc] + 1e-5f) + be[oc];
  return fmaxf(val, 0.0f);
}

// ---------------------------------------------------------------------------
// Wave64 max via DPP + readlane(63). Identity = -1.0f.
// ---------------------------------------------------------------------------
__device__ __forceinline__ float wave64_max(float x) {
  const int NEG1 = 0xbf800000;
  int v;
  v = __builtin_amdgcn_update_dpp(NEG1, __float_as_int(x), 0x111, 0xf, 0xf, false);
  x = fmaxf(x, __int_as_float(v));
  v = __builtin_amdgcn_update_dpp(NEG1, __float_as_int(x), 0x112, 0xf, 0xf, false);
  x = fmaxf(x, __int_as_float(v));
  v = __builtin_amdgcn_update_dpp(NEG1, __float_as_int(x), 0x114, 0xf, 0xf, false);
  x = fmaxf(x, __int_as_float(v));
  v = __builtin_amdgcn_update_dpp(NEG1, __float_as_int(x), 0x118, 0xf, 0xf, false);
  x = fmaxf(x, __int_as_float(v));
  v = __builtin_amdgcn_update_dpp(NEG1, __float_as_int(x), 0x142, 0xa, 0xf, false);
  x = fmaxf(x, __int_as_float(v));
  v = __builtin_amdgcn_update_dpp(NEG1, __float_as_int(x), 0x143, 0xc, 0xf, false);
  x = fmaxf(x, __int_as_float(v));
  return __int_as_float(__builtin_amdgcn_readlane(__float_as_int(x), 63));
}

// ---------------------------------------------------------------------------
// Kernel 1: FPS v7. 256 threads x 16 points (4 waves = 1/SIMD; aggregate
// VALU issue unchanged vs v5). Critical-path cuts vs v5: 4-wave barrier
// (was 8), 4-slot reduction, winner COORDS carried in the float4 record
// (kills the 3 uniform s_x[far] LDS lookups). __launch_bounds__(256,1)
// pins the allocator to 1 wave/EU so the ~100 VGPRs live in registers
// (R8/R9 cliffs both came from occupancy-greedy allocation).
// Selection semantics identical to verified v1-v5: exact __f*_rn distance
// order, per-thread first-max (ascending j, contiguous 16-pt ownership),
// wave ffs(ballot), ascending-wave left-favored tournament.
// ---------------------------------------------------------------------------
__global__ __launch_bounds__(256, 1) void fps_kernel(
    const float* __restrict__ xyz, int* __restrict__ fps_idx,
    float* __restrict__ nxyz, float* __restrict__ out0) {
  const int b = blockIdx.x;
  const int t = threadIdx.x;
  const int lane = t & 63, wid = t >> 6;   // wid 0..3
  const float* xb = xyz + (size_t)b * 3 * NPT;

  __shared__ __align__(16) float s_rv[2][4][4];  // per wave: val,x,y,z
  __shared__ int s_ri[2][4];
  __shared__ float s_ox[NS], s_oy[NS], s_oz[NS];
  __shared__ int s_fi[NS];

  float px[16], py[16], pz[16], dist[16];
  const int base = t * 16;
#pragma unroll
  for (int j4 = 0; j4 < 4; ++j4) {
    float4 vx = *(const float4*)&xb[base + j4 * 4];
    float4 vy = *(const float4*)&xb[NPT + base + j4 * 4];
    float4 vz = *(const float4*)&xb[2 * NPT + base + j4 * 4];
    px[j4 * 4 + 0] = vx.x; px[j4 * 4 + 1] = vx.y;
    px[j4 * 4 + 2] = vx.z; px[j4 * 4 + 3] = vx.w;
    py[j4 * 4 + 0] = vy.x; py[j4 * 4 + 1] = vy.y;
    py[j4 * 4 + 2] = vy.z; py[j4 * 4 + 3] = vy.w;
    pz[j4 * 4 + 0] = vz.x; pz[j4 * 4 + 1] = vz.y;
    pz[j4 * 4 + 2] = vz.z; pz[j4 * 4 + 3] = vz.w;
  }
#pragma unroll
  for (int j = 0; j < 16; ++j) dist[j] = 1e10f;

  int far = 0;
  float cx = xb[0], cy = xb[NPT], cz = xb[2 * NPT];

  for (int s = 0; s < NS; ++s) {
    if (t == 0) {
      s_ox[s] = cx; s_oy[s] = cy; s_oz[s] = cz; s_fi[s] = far;
    }

    // min-update distances + per-thread first-max (ascending index order)
    float bv = -1.0f, bx = 0.f, by = 0.f, bz = 0.f;
    int bi = 0;
#pragma unroll
    for (int j = 0; j < 16; ++j) {
      float dx = __fsub_rn(px[j], cx);
      float dy = __fsub_rn(py[j], cy);
      float dz = __fsub_rn(pz[j], cz);
      float d = __fadd_rn(__fadd_rn(__fmul_rn(dx, dx), __fmul_rn(dy, dy)),
                          __fmul_rn(dz, dz));
      float nd = fminf(dist[j], d);
      dist[j] = nd;
      bool g = nd > bv;
      bi = g ? (base + j) : bi;
      bx = g ? px[j] : bx;
      by = g ? py[j] : by;
      bz = g ? pz[j] : bz;
      bv = g ? nd : bv;
    }

    // wave-level max; first set lane = smallest index (contiguous ownership)
    float mv = wave64_max(bv);
    unsigned long long mmask = __ballot(bv == mv);
    int src = __ffsll(mmask) - 1;
    int wi = __shfl(bi, src);
    float wx = __shfl(bx, src);
    float wy = __shfl(by, src);
    float wz = __shfl(bz, src);

    const int p = s & 1;
    if (lane == 0) {
      *(float4*)&s_rv[p][wid][0] = make_float4(mv, wx, wy, wz);
      s_ri[p][wid] = wi;
    }
    __syncthreads();

    // 4-slot left-favored tournament (right wins only on strict >)
    float4 r0 = *(const float4*)&s_rv[p][0][0];
    float4 r1 = *(const float4*)&s_rv[p][1][0];
    float4 r2 = *(const float4*)&s_rv[p][2][0];
    float4 r3 = *(const float4*)&s_rv[p][3][0];
    int i0 = s_ri[p][0], i1 = s_ri[p][1], i2 = s_ri[p][2], i3 = s_ri[p][3];
    bool g01 = r1.x > r0.x;
    float4 w01 = g01 ? r1 : r0;
    int j01 = g01 ? i1 : i0;
    bool g23 = r3.x > r2.x;
    float4 w23 = g23 ? r3 : r2;
    int j23 = g23 ? i3 : i2;
    bool gf = w23.x > w01.x;
    float4 wf = gf ? w23 : w01;
    far = gf ? j23 : j01;
    cx = wf.y; cy = wf.z; cz = wf.w;
  }

  __syncthreads();
  for (int i = t; i < NS; i += 256) {
    float X = s_ox[i], Y = s_oy[i], Z = s_oz[i];
    out0[((size_t)b * 3 + 0) * NS + i] = X;
    out0[((size_t)b * 3 + 1) * NS + i] = Y;
    out0[((size_t)b * 3 + 2) * NS + i] = Z;
    nxyz[((size_t)b * NS + i) * 3 + 0] = X;
    nxyz[((size_t)b * NS + i) * 3 + 1] = Y;
    nxyz[((size_t)b * NS + i) * 3 + 2] = Z;
    fps_idx[b * NS + i] = s_fi[i];
  }
}

// ---------------------------------------------------------------------------
// Kernel 2: center-point MLP + center half of attention scores. (unchanged)
// ---------------------------------------------------------------------------
__global__ __launch_bounds__(64) void center_kernel(
    const float* __restrict__ points, const float* __restrict__ nxyz,
    const int* __restrict__ fps_idx,
    const float* __restrict__ w0, const float* __restrict__ b0,
    const float* __restrict__ g0, const float* __restrict__ be0,
    const float* __restrict__ m0, const float* __restrict__ v0,
    const float* __restrict__ w1, const float* __restrict__ b1,
    const float* __restrict__ g1, const float* __restrict__ be1,
    const float* __restrict__ m1, const float* __restrict__ v1,
    const float* __restrict__ w2, const float* __restrict__ b2,
    const float* __restrict__ g2, const float* __restrict__ be2,
    const float* __restrict__ m2, const float* __restrict__ v2,
    const float* __restrict__ a, float* __restrict__ ceA) {
  const int bs = blockIdx.x;
  const int b = bs >> 10;
  const int t = threadIdx.x;

  __shared__ float ci[9];
  __shared__ float ch1[64];
  __shared__ float ch2[64];
  __shared__ float ch3[128];

  if (t < 9) {
    ci[t] = (t < 3) ? nxyz[(size_t)bs * 3 + t]
                    : points[((size_t)b * DIN + (t - 3)) * NPT + fps_idx[bs]];
  }
  __syncthreads();
  {
    float acc = 0.f;
#pragma unroll
    for (int c = 0; c < 9; ++c) acc = fmaf(ci[c], w0[t * 9 + c], acc);
    ch1[t] = bnrelu(acc, b0, g0, be0, m0, v0, t);
  }
  __syncthreads();
  {
    float acc = 0.f;
#pragma unroll 8
    for (int c = 0; c < 64; ++c) acc = fmaf(ch1[c], w1[t * 64 + c], acc);
    ch2[t] = bnrelu(acc, b1, g1, be1, m1, v1, t);
  }
  __syncthreads();
  for (int oc = t; oc < 128; oc += 64) {
    float acc = 0.f;
#pragma unroll 8
    for (int c = 0; c < 64; ++c) acc = fmaf(ch2[c], w2[oc * 64 + c], acc);
    ch3[oc] = bnrelu(acc, b2, g2, be2, m2, v2, oc);
  }
  __syncthreads();
  for (int oc = t; oc < 128; oc += 64) {
    float acc = 0.f;
#pragma unroll 8
    for (int c = 0; c < 128; ++c) acc = fmaf(ch3[c], a[(3 + c) * 128 + oc], acc);
    ceA[(size_t)bs * 128 + oc] = acc;
  }
}

// ---------------------------------------------------------------------------
// Kernel 3: standalone ball query + gather (unchanged, verified).
// ---------------------------------------------------------------------------
__global__ __launch_bounds__(256) void ballq_kernel(
    const float* __restrict__ xyz, const float* __restrict__ nxyz,
    float4* __restrict__ gq) {
  const int bs = blockIdx.x;
  const int b = bs >> 10;
  const int t = threadIdx.x;
  const int lane = t & 63;
  const int wid = t >> 6;

  __shared__ int s_widx[4][NK];
  __shared__ int s_wc[4];

  const float* xb = xyz + (size_t)b * 3 * NPT;
  const float cx = nxyz[(size_t)bs * 3 + 0];
  const float cy = nxyz[(size_t)bs * 3 + 1];
  const float cz = nxyz[(size_t)bs * 3 + 2];

  {
    const float R2 = (float)(0.15 * 0.15);
    float s2c = __fadd_rn(__fadd_rn(__fmul_rn(cx, cx), __fmul_rn(cy, cy)),
                          __fmul_rn(cz, cz));
    int wcnt = 0;
    for (int g = 0; g < 16; ++g) {
      int n = wid * 1024 + g * 64 + lane;
      float x = xb[n];
      float y = xb[NPT + n];
      float z = xb[2 * NPT + n];
      float pn2 = __fadd_rn(__fadd_rn(__fmul_rn(x, x), __fmul_rn(y, y)),
                            __fmul_rn(z, z));
      float dot = fmaf(cz, z, fmaf(cy, y, __fmul_rn(cx, x)));
      float sqr = __fsub_rn(__fadd_rn(s2c, pn2), __fmul_rn(2.0f, dot));
      bool hit = !(sqr > R2);
      unsigned long long mm = __ballot(hit);
      int pos = wcnt + __popcll(mm & ((1ull << lane) - 1ull));
      if (hit && pos < NK) s_widx[wid][pos] = n;
      wcnt += __popcll(mm);
      if (wcnt >= NK) break;  // wave-uniform
    }
    if (lane == 0) s_wc[wid] = (wcnt < NK) ? wcnt : NK;
  }
  __syncthreads();

  if (t < NK) {
    int c0 = s_wc[0], c1 = s_wc[1], c2 = s_wc[2], c3 = s_wc[3];
    int total = c0 + c1 + c2 + c3;
    int cc[4] = {c0, c1, c2, c3};
    int p = (t < total) ? t : 0;  // pad misses with overall-first hit
    int w = 0;
    while (w < 3 && p >= cc[w]) { p -= cc[w]; ++w; }
    int n = s_widx[w][p];
    float gx = __fsub_rn(xb[n], cx);
    float gy = __fsub_rn(xb[NPT + n], cy);
    float gz = __fsub_rn(xb[2 * NPT + n], cz);
    gq[(size_t)bs * NK + t] = make_float4(gx, gy, gz, __int_as_float(n));
  }
}

// ---------------------------------------------------------------------------
// Kernel 4 (mega v5): unchanged from R10 (verified; ~320 us).
// ---------------------------------------------------------------------------
__global__ __launch_bounds__(MEGA_THREADS) void mega_kernel(
    const float* __restrict__ points, const float* __restrict__ ceA,
    const float4* __restrict__ gq,
    const float* __restrict__ w0, const float* __restrict__ b0,
    const float* __restrict__ g0, const float* __restrict__ be0,
    const float* __restrict__ m0, const float* __restrict__ v0,
    const float* __restrict__ w1, const float* __restrict__ b1,
    const float* __restrict__ g1, const float* __restrict__ be1,
    const float* __restrict__ m1, const float* __restrict__ v1,
    const float* __restrict__ w2, const float* __restrict__ b2,
    const float* __restrict__ g2, const float* __restrict__ be2,
    const float* __restrict__ m2, const float* __restrict__ v2,
    const float* __restrict__ a, float* __restrict__ out1) {
  extern __shared__ float lds[];
  float* s_a  = lds + OFF_A;
  float* s_w1 = lds + OFF_W1;
  float* s_w2 = lds + OFF_W2;
  float* s_w0 = lds + OFF_W0;
  float* s_h1 = lds + OFF_H1;
  float* s_h2 = lds + OFF_H2;
  float* s_u  = lds + OFF_U;

  const int t = threadIdx.x;
  const int k = t & 31;             // C-phase neighbor row
  const int g16 = t >> 5;           // C-phase oc group 0..15
  const int kk = t & 15;            // D/E/F k base (rows kk, kk+16)
  const int gg = t >> 4;            // D/E/F oc group 0..31

  // ---- stage weights into LDS (once per block) ----
  {
    const float4* srcA = (const float4*)a;
    float4* dstA = (float4*)s_a;
    for (int i = t; i < 4192; i += MEGA_THREADS) dstA[i] = srcA[i];
    const float4* src1 = (const float4*)w1;
    float4* dst1 = (float4*)s_w1;
    for (int i = t; i < 1024; i += MEGA_THREADS) dst1[i] = src1[i];
    const float4* src2 = (const float4*)w2;
    float4* dst2 = (float4*)s_w2;
    for (int i = t; i < 2048; i += MEGA_THREADS) dst2[i] = src2[i];
    for (int i = t; i < 576; i += MEGA_THREADS) s_w0[i] = w0[i];
  }
  __syncthreads();

  const int bs0 = blockIdx.x * QPB;

  float4 gv = gq[(size_t)bs0 * NK + k];
  float pts[6];
  {
    int n = __float_as_int(gv.w);
    const float* pb = points + (size_t)(bs0 >> 10) * DIN * NPT + n;
#pragma unroll
    for (int c = 0; c < 6; ++c) pts[c] = pb[(size_t)c * NPT];
  }

  for (int q = 0; q < QPB; ++q) {
    const int bs = bs0 + q;
    const int b = bs >> 10;
    const int s = bs & 1023;

    const int qn = (q + 1 < QPB) ? (q + 1) : q;
    const int bsn = bs0 + qn;
    float4 gv_next = gq[(size_t)bsn * NK + k];

    // ---- C: layer 1, 9 -> 64 (k = t&31, oc = g16*4 + j) ----
    {
      float in0[9];
      in0[0] = gv.x; in0[1] = gv.y; in0[2] = gv.z;
#pragma unroll
      for (int c = 0; c < 6; ++c) in0[3 + c] = pts[c];
      int oc0 = g16 * 4;
      float acc[4];
#pragma unroll
      for (int j = 0; j < 4; ++j) {
        float a0 = 0.f;
#pragma unroll
        for (int c = 0; c < 9; ++c)
          a0 = fmaf(in0[c], s_w0[(oc0 + j) * 9 + c], a0);
        acc[j] = bnrelu(a0, b0, g0, be0, m0, v0, oc0 + j);
      }
      *(float4*)&s_h1[k * 68 + oc0] = make_float4(acc[0], acc[1], acc[2], acc[3]);
    }
    __syncthreads();  // B1

    float pts_next[6];
    {
      int nn = __float_as_int(gv_next.w);
      const float* pbn = points + (size_t)(bsn >> 10) * DIN * NPT + nn;
#pragma unroll
      for (int c = 0; c < 6; ++c) pts_next[c] = pbn[(size_t)c * NPT];
    }

    // ---- D: layer 2, 64 -> 64; rows kk & kk+16, oc = gg*2 + j ----
    {
      int oc0 = gg * 2;
      float a0[2] = {0.f, 0.f}, a1[2] = {0.f, 0.f};
      const float4* row0 = (const float4*)&s_h1[kk * 68];
      const float4* row1 = (const float4*)&s_h1[(kk + 16) * 68];
#pragma unroll 4
      for (int c4 = 0; c4 < 16; ++c4) {
        float4 h0 = row0[c4];
        float4 h1 = row1[c4];
#pragma unroll
        for (int j = 0; j < 2; ++j) {
          float4 wv = *(const float4*)&s_w1[(oc0 + j) * 64 + c4 * 4];
          a0[j] = fmaf(h0.x, wv.x, a0[j]);
          a0[j] = fmaf(h0.y, wv.y, a0[j]);
          a0[j] = fmaf(h0.z, wv.z, a0[j]);
          a0[j] = fmaf(h0.w, wv.w, a0[j]);
          a1[j] = fmaf(h1.x, wv.x, a1[j]);
          a1[j] = fmaf(h1.y, wv.y, a1[j]);
          a1[j] = fmaf(h1.z, wv.z, a1[j]);
          a1[j] = fmaf(h1.w, wv.w, a1[j]);
        }
      }
#pragma unroll
      for (int j = 0; j < 2; ++j) {
        a0[j] = bnrelu(a0[j], b1, g1, be1, m1, v1, oc0 + j);
        a1[j] = bnrelu(a1[j], b1, g1, be1, m1, v1, oc0 + j);
      }
      s_h2[kk * 68 + oc0] = a0[0];
      s_h2[kk * 68 + oc0 + 1] = a0[1];
      s_h2[(kk + 16) * 68 + oc0] = a1[0];
      s_h2[(kk + 16) * 68 + oc0 + 1] = a1[1];
    }
    __syncthreads();  // B2

    // ---- E: layer 3, 64 -> 128; rows kk & kk+16, oc = gg*4 + j ----
    {
      int oc0 = gg * 4;
      float a0[4] = {0.f, 0.f, 0.f, 0.f}, a1[4] = {0.f, 0.f, 0.f, 0.f};
      const float4* row0 = (const float4*)&s_h2[kk * 68];
      const float4* row1 = (const float4*)&s_h2[(kk + 16) * 68];
#pragma unroll 4
      for (int c4 = 0; c4 < 16; ++c4) {
        float4 h0 = row0[c4];
        float4 h1 = row1[c4];
#pragma unroll
        for (int j = 0; j < 4; ++j) {
          float4 wv = *(const float4*)&s_w2[(oc0 + j) * 64 + c4 * 4];
          a0[j] = fmaf(h0.x, wv.x, a0[j]);
          a0[j] = fmaf(h0.y, wv.y, a0[j]);
          a0[j] = fmaf(h0.z, wv.z, a0[j]);
          a0[j] = fmaf(h0.w, wv.w, a0[j]);
          a1[j] = fmaf(h1.x, wv.x, a1[j]);
          a1[j] = fmaf(h1.y, wv.y, a1[j]);
          a1[j] = fmaf(h1.z, wv.z, a1[j]);
          a1[j] = fmaf(h1.w, wv.w, a1[j]);
        }
      }
#pragma unroll
      for (int j = 0; j < 4; ++j) {
        a0[j] = bnrelu(a0[j], b2, g2, be2, m2, v2, oc0 + j);
        a1[j] = bnrelu(a1[j], b2, g2, be2, m2, v2, oc0 + j);
      }
      *(float4*)&s_u[kk * 132 + oc0] = make_float4(a0[0], a0[1], a0[2], a0[3]);
      *(float4*)&s_u[(kk + 16) * 132 + oc0] =
          make_float4(a1[0], a1[1], a1[2], a1[3]);
      if (t < NK) {
        s_u[t * 132 + 128] = gv.x;
        s_u[t * 132 + 129] = gv.y;
        s_u[t * 132 + 130] = gv.z;
        s_u[t * 132 + 131] = 0.f;
      }
    }
    __syncthreads();  // B3

    // ---- F: attention; rows kk & kk+16, oc = gg*4 + j ----
    {
      int oc0 = gg * 4;
      float a0[4] = {0.f, 0.f, 0.f, 0.f}, a1[4] = {0.f, 0.f, 0.f, 0.f};
      const float4* urow0 = (const float4*)&s_u[kk * 132];
      const float4* urow1 = (const float4*)&s_u[(kk + 16) * 132];
      for (int r4 = 0; r4 < 33; ++r4) {
        float4 uv0 = urow0[r4];
        float4 uv1 = urow1[r4];
        int r = r4 * 4;
#pragma unroll
        for (int cc = 0; cc < 4; ++cc) {
          int rr = r + cc;
          int arow = (rr < 128) ? (rr + 3) : (rr - 128);  // rr==131 -> a[3]*0
          float uc0 = (cc == 0) ? uv0.x : (cc == 1) ? uv0.y : (cc == 2) ? uv0.z : uv0.w;
          float uc1 = (cc == 0) ? uv1.x : (cc == 1) ? uv1.y : (cc == 2) ? uv1.z : uv1.w;
          float4 av = *(const float4*)&s_a[arow * 128 + oc0];
          a0[0] = fmaf(uc0, av.x, a0[0]);
          a0[1] = fmaf(uc0, av.y, a0[1]);
          a0[2] = fmaf(uc0, av.z, a0[2]);
          a0[3] = fmaf(uc0, av.w, a0[3]);
          a1[0] = fmaf(uc1, av.x, a1[0]);
          a1[1] = fmaf(uc1, av.y, a1[1]);
          a1[2] = fmaf(uc1, av.z, a1[2]);
          a1[3] = fmaf(uc1, av.w, a1[3]);
        }
      }

      float4 cv = *(const float4*)&ceA[(size_t)bs * 128 + oc0];
      float4 h0v = *(const float4*)&s_u[kk * 132 + oc0];
      float4 h1v = *(const float4*)&s_u[(kk + 16) * 132 + oc0];
      float ce[4] = {cv.x, cv.y, cv.z, cv.w};
      float h0[4] = {h0v.x, h0v.y, h0v.z, h0v.w};
      float h1[4] = {h1v.x, h1v.y, h1v.z, h1v.w};

      float* outb = out1 + (size_t)b * 128 * NS + s;
#pragma unroll
      for (int j = 0; j < 4; ++j) {
        float e0 = ce[j] - a0[j];
        float e1 = ce[j] - a1[j];
        e0 = (e0 >= 0.f) ? e0 : 0.2f * e0;  // leaky relu alpha=0.2
        e1 = (e1 >= 0.f) ? e1 : 0.2f * e1;
        float mx = fmaxf(e0, e1);
#pragma unroll
        for (int off = 8; off > 0; off >>= 1)
          mx = fmaxf(mx, __shfl_xor(mx, off));   // stays in 16-lane group
        float p0 = expf(e0 - mx);
        float p1 = expf(e1 - mx);
        float num = p0 * h0[j] + p1 * h1[j];
        float den = p0 + p1;
#pragma unroll
        for (int off = 8; off > 0; off >>= 1) {
          num += __shfl_xor(num, off);
          den += __shfl_xor(den, off);
        }
        if (kk == 0) outb[(size_t)(oc0 + j) * NS] = num / den;
      }
    }
    // no trailing barrier needed (see R7 proof)

    gv = gv_next;
#pragma unroll
    for (int c = 0; c < 6; ++c) pts[c] = pts_next[c];
  }
}

// ---------------------------------------------------------------------------
extern "C" void kernel_launch(void* const* d_in, const int* in_sizes, int n_in,
                              void* d_out, int out_size, void* d_ws,
                              size_t ws_size, hipStream_t stream) {
  (void)in_sizes; (void)n_in; (void)out_size; (void)ws_size;
  const float* xyz = (const float*)d_in[0];
  const float* points = (const float*)d_in[1];
  const float* w0 = (const float*)d_in[2];
  const float* b0 = (const float*)d_in[3];
  const float* g0 = (const float*)d_in[4];
  const float* be0 = (const float*)d_in[5];
  const float* m0 = (const float*)d_in[6];
  const float* v0 = (const float*)d_in[7];
  const float* w1 = (const float*)d_in[8];
  const float* b1 = (const float*)d_in[9];
  const float* g1 = (const float*)d_in[10];
  const float* be1 = (const float*)d_in[11];
  const float* m1 = (const float*)d_in[12];
  const float* v1 = (const float*)d_in[13];
  const float* w2 = (const float*)d_in[14];
  const float* b2 = (const float*)d_in[15];
  const float* g2 = (const float*)d_in[16];
  const float* be2 = (const float*)d_in[17];
  const float* m2 = (const float*)d_in[18];
  const float* v2 = (const float*)d_in[19];
  const float* a = (const float*)d_in[20];

  float* out0 = (float*)d_out;                  // [B,3,S]
  float* out1 = out0 + (size_t)NB * 3 * NS;     // [B,128,S]

  int* fps = (int*)d_ws;                                        // 32 KB
  float* nxyz = (float*)((char*)d_ws + 32768);                  // 96 KB
  float* ceA = (float*)((char*)d_ws + 131072);                  // 4 MB
  float4* gq = (float4*)((char*)d_ws + 131072 + 4194304);       // 4 MB

  hipFuncSetAttribute(reinterpret_cast<const void*>(mega_kernel),
                      hipFuncAttributeMaxDynamicSharedMemorySize, SMEM_BYTES);

  fps_kernel<<<NB, 256, 0, stream>>>(xyz, fps, nxyz, out0);
  ballq_kernel<<<NB * NS, 256, 0, stream>>>(xyz, nxyz, gq);
  center_kernel<<<NB * NS, 64, 0, stream>>>(points, nxyz, fps,
      w0, b0, g0, be0, m0, v0, w1, b1, g1, be1, m1, v1,
      w2, b2, g2, be2, m2, v2, a, ceA);
  mega_kernel<<<NB * NS / QPB, MEGA_THREADS, SMEM_BYTES, stream>>>(
      points, ceA, gq,
      w0, b0, g0, be0, m0, v0, w1, b1, g1, be1, m1, v1,
      w2, b2, g2, be2, m2, v2, a, out1);
}

// Round 12
// 1141.792 us; speedup vs baseline: 1.1016x; 1.1016x over previous
//
#include <hip/hip_runtime.h>

#define NB  8
#define NPT 4096
#define NS  1024
#define NK  32
#define DIN 6
#define QPB 32          // queries per mega-block
#define MEGA_THREADS 512

typedef float v2f __attribute__((ext_vector_type(2)));

// mega LDS float offsets
#define OFF_A   0            // 131*128 = 16768
#define OFF_W1  16768        // 64*64   = 4096
#define OFF_W2  20864        // 128*64  = 8192
#define OFF_W0  29056        // 64*9    = 576
#define OFF_H1  29632        // 32*68   = 2176
#define OFF_H2  31808        // 32*68   = 2176
#define OFF_U   33984        // 32*132  = 4224
#define FLT_TOT 38208
#define SMEM_BYTES (FLT_TOT * 4)   // 152832 B <= 160 KiB

// ---------------------------------------------------------------------------
__device__ __forceinline__ float bnrelu(float acc, const float* __restrict__ bb,
                                        const float* __restrict__ gg,
                                        const float* __restrict__ be,
                                        const float* __restrict__ mm,
                                        const float* __restrict__ vv, int oc) {
  float t = (acc + bb[oc]) - mm[oc];
  float val = gg[oc] * t * rsqrtf(vv[oc] + 1e-5f) + be[oc];
  return fmaxf(val, 0.0f);
}

// ---------------------------------------------------------------------------
// Wave64 max via DPP + readlane(63). Identity = -1.0f.
// ---------------------------------------------------------------------------
__device__ __forceinline__ float wave64_max(float x) {
  const int NEG1 = 0xbf800000;
  int v;
  v = __builtin_amdgcn_update_dpp(NEG1, __float_as_int(x), 0x111, 0xf, 0xf, false);
  x = fmaxf(x, __int_as_float(v));
  v = __builtin_amdgcn_update_dpp(NEG1, __float_as_int(x), 0x112, 0xf, 0xf, false);
  x = fmaxf(x, __int_as_float(v));
  v = __builtin_amdgcn_update_dpp(NEG1, __float_as_int(x), 0x114, 0xf, 0xf, false);
  x = fmaxf(x, __int_as_float(v));
  v = __builtin_amdgcn_update_dpp(NEG1, __float_as_int(x), 0x118, 0xf, 0xf, false);
  x = fmaxf(x, __int_as_float(v));
  v = __builtin_amdgcn_update_dpp(NEG1, __float_as_int(x), 0x142, 0xa, 0xf, false);
  x = fmaxf(x, __int_as_float(v));
  v = __builtin_amdgcn_update_dpp(NEG1, __float_as_int(x), 0x143, 0xc, 0xf, false);
  x = fmaxf(x, __int_as_float(v));
  return __int_as_float(__builtin_amdgcn_readlane(__float_as_int(x), 63));
}

// ---------------------------------------------------------------------------
// Kernel 1: FPS v8 = verified v5 structure (512 thr x 8 pts, 660 us) with the
// distance update moved to packed fp32 (<2 x float> -> v_pk_mul/add_f32).
// fp contract(off) pragma keeps mul/add un-fused (bit-exact vs scalar rn);
// op order add(add(mul,mul),mul) and ascending .x/.y selection preserve the
// verified first-max semantics. fps is issue-bound (72% VALU busy on its
// active CUs), so halving the dist-update stream is the lever.
// ---------------------------------------------------------------------------
__global__ __launch_bounds__(512) void fps_kernel(const float* __restrict__ xyz,
                                                  int* __restrict__ fps_idx,
                                                  float* __restrict__ nxyz,
                                                  float* __restrict__ out0) {
#pragma clang fp contract(off)
  const int b = blockIdx.x;
  const int t = threadIdx.x;
  const int lane = t & 63, wid = t >> 6;
  const float* xb = xyz + (size_t)b * 3 * NPT;

  __shared__ float s_x[NPT], s_y[NPT], s_z[NPT];
  __shared__ __align__(16) float s_red[2][8][2];
  __shared__ float s_ox[NS], s_oy[NS], s_oz[NS];
  __shared__ int s_fi[NS];

  v2f px[4], py[4], pz[4], dist[4];
  const int base = t * 8;
#pragma unroll
  for (int j4 = 0; j4 < 2; ++j4) {
    float4 vx = *(const float4*)&xb[base + j4 * 4];
    float4 vy = *(const float4*)&xb[NPT + base + j4 * 4];
    float4 vz = *(const float4*)&xb[2 * NPT + base + j4 * 4];
    px[j4 * 2 + 0] = (v2f){vx.x, vx.y}; px[j4 * 2 + 1] = (v2f){vx.z, vx.w};
    py[j4 * 2 + 0] = (v2f){vy.x, vy.y}; py[j4 * 2 + 1] = (v2f){vy.z, vy.w};
    pz[j4 * 2 + 0] = (v2f){vz.x, vz.y}; pz[j4 * 2 + 1] = (v2f){vz.z, vz.w};
  }
#pragma unroll
  for (int j = 0; j < 4; ++j) dist[j] = (v2f){1e10f, 1e10f};

  for (int i = t; i < NPT; i += 512) {
    s_x[i] = xb[i];
    s_y[i] = xb[NPT + i];
    s_z[i] = xb[2 * NPT + i];
  }
  __syncthreads();

  int far = 0;
  float cx = xb[0], cy = xb[NPT], cz = xb[2 * NPT];

  for (int s = 0; s < NS; ++s) {
    if (t == 0) {
      s_ox[s] = cx; s_oy[s] = cy; s_oz[s] = cz; s_fi[s] = far;
    }

    // packed distance update + ascending-order first-max selection
    v2f c2x = cx, c2y = cy, c2z = cz;   // splat
    float bv = -1.0f;
    int bi = 0;
#pragma unroll
    for (int j = 0; j < 4; ++j) {
      v2f dx = px[j] - c2x;
      v2f dy = py[j] - c2y;
      v2f dz = pz[j] - c2z;
      v2f m0 = dx * dx;
      v2f m1 = dy * dy;
      v2f m2 = dz * dz;
      v2f d = (m0 + m1) + m2;           // add(add(mul,mul),mul) == scalar v5
      v2f nd = __builtin_elementwise_min(dist[j], d);
      dist[j] = nd;
      float n0 = nd.x, n1 = nd.y;
      bool g0 = n0 > bv;
      bi = g0 ? (base + 2 * j) : bi;
      bv = g0 ? n0 : bv;
      bool g1 = n1 > bv;
      bi = g1 ? (base + 2 * j + 1) : bi;
      bv = g1 ? n1 : bv;
    }

    float mv = wave64_max(bv);
    unsigned long long mmask = __ballot(bv == mv);
    int src = __ffsll(mmask) - 1;
    int wi = __shfl(bi, src);

    const int p = s & 1;
    if (lane == 0) {
      s_red[p][wid][0] = mv;
      s_red[p][wid][1] = __int_as_float(wi);
    }
    __syncthreads();

    float4 q0 = *(const float4*)&s_red[p][0][0];
    float4 q1 = *(const float4*)&s_red[p][2][0];
    float4 q2 = *(const float4*)&s_red[p][4][0];
    float4 q3 = *(const float4*)&s_red[p][6][0];
    // tournament: right side wins only on strict > => first max overall
    float va, vb, vc, vd; int ia, ib, ic, id;
    { bool g = q0.z > q0.x; va = g ? q0.z : q0.x;
      ia = g ? __float_as_int(q0.w) : __float_as_int(q0.y); }
    { bool g = q1.z > q1.x; vb = g ? q1.z : q1.x;
      ib = g ? __float_as_int(q1.w) : __float_as_int(q1.y); }
    { bool g = q2.z > q2.x; vc = g ? q2.z : q2.x;
      ic = g ? __float_as_int(q2.w) : __float_as_int(q2.y); }
    { bool g = q3.z > q3.x; vd = g ? q3.z : q3.x;
      id = g ? __float_as_int(q3.w) : __float_as_int(q3.y); }
    { bool g = vb > va; va = g ? vb : va; ia = g ? ib : ia; }
    { bool g = vd > vc; vc = g ? vd : vc; ic = g ? id : ic; }
    { bool g = vc > va; va = g ? vc : va; ia = g ? ic : ia; }
    far = ia;
    cx = s_x[far]; cy = s_y[far]; cz = s_z[far];
  }

  __syncthreads();
  for (int i = t; i < NS; i += 512) {
    float X = s_ox[i], Y = s_oy[i], Z = s_oz[i];
    out0[((size_t)b * 3 + 0) * NS + i] = X;
    out0[((size_t)b * 3 + 1) * NS + i] = Y;
    out0[((size_t)b * 3 + 2) * NS + i] = Z;
    nxyz[((size_t)b * NS + i) * 3 + 0] = X;
    nxyz[((size_t)b * NS + i) * 3 + 1] = Y;
    nxyz[((size_t)b * NS + i) * 3 + 2] = Z;
    fps_idx[b * NS + i] = s_fi[i];
  }
}

// ---------------------------------------------------------------------------
// Kernel 2: center-point MLP + center half of attention scores. (unchanged)
// ---------------------------------------------------------------------------
__global__ __launch_bounds__(64) void center_kernel(
    const float* __restrict__ points, const float* __restrict__ nxyz,
    const int* __restrict__ fps_idx,
    const float* __restrict__ w0, const float* __restrict__ b0,
    const float* __restrict__ g0, const float* __restrict__ be0,
    const float* __restrict__ m0, const float* __restrict__ v0,
    const float* __restrict__ w1, const float* __restrict__ b1,
    const float* __restrict__ g1, const float* __restrict__ be1,
    const float* __restrict__ m1, const float* __restrict__ v1,
    const float* __restrict__ w2, const float* __restrict__ b2,
    const float* __restrict__ g2, const float* __restrict__ be2,
    const float* __restrict__ m2, const float* __restrict__ v2,
    const float* __restrict__ a, float* __restrict__ ceA) {
  const int bs = blockIdx.x;
  const int b = bs >> 10;
  const int t = threadIdx.x;

  __shared__ float ci[9];
  __shared__ float ch1[64];
  __shared__ float ch2[64];
  __shared__ float ch3[128];

  if (t < 9) {
    ci[t] = (t < 3) ? nxyz[(size_t)bs * 3 + t]
                    : points[((size_t)b * DIN + (t - 3)) * NPT + fps_idx[bs]];
  }
  __syncthreads();
  {
    float acc = 0.f;
#pragma unroll
    for (int c = 0; c < 9; ++c) acc = fmaf(ci[c], w0[t * 9 + c], acc);
    ch1[t] = bnrelu(acc, b0, g0, be0, m0, v0, t);
  }
  __syncthreads();
  {
    float acc = 0.f;
#pragma unroll 8
    for (int c = 0; c < 64; ++c) acc = fmaf(ch1[c], w1[t * 64 + c], acc);
    ch2[t] = bnrelu(acc, b1, g1, be1, m1, v1, t);
  }
  __syncthreads();
  for (int oc = t; oc < 128; oc += 64) {
    float acc = 0.f;
#pragma unroll 8
    for (int c = 0; c < 64; ++c) acc = fmaf(ch2[c], w2[oc * 64 + c], acc);
    ch3[oc] = bnrelu(acc, b2, g2, be2, m2, v2, oc);
  }
  __syncthreads();
  for (int oc = t; oc < 128; oc += 64) {
    float acc = 0.f;
#pragma unroll 8
    for (int c = 0; c < 128; ++c) acc = fmaf(ch3[c], a[(3 + c) * 128 + oc], acc);
    ceA[(size_t)bs * 128 + oc] = acc;
  }
}

// ---------------------------------------------------------------------------
// Kernel 3: standalone ball query + gather (unchanged, verified).
// ---------------------------------------------------------------------------
__global__ __launch_bounds__(256) void ballq_kernel(
    const float* __restrict__ xyz, const float* __restrict__ nxyz,
    float4* __restrict__ gq) {
  const int bs = blockIdx.x;
  const int b = bs >> 10;
  const int t = threadIdx.x;
  const int lane = t & 63;
  const int wid = t >> 6;

  __shared__ int s_widx[4][NK];
  __shared__ int s_wc[4];

  const float* xb = xyz + (size_t)b * 3 * NPT;
  const float cx = nxyz[(size_t)bs * 3 + 0];
  const float cy = nxyz[(size_t)bs * 3 + 1];
  const float cz = nxyz[(size_t)bs * 3 + 2];

  {
    const float R2 = (float)(0.15 * 0.15);
    float s2c = __fadd_rn(__fadd_rn(__fmul_rn(cx, cx), __fmul_rn(cy, cy)),
                          __fmul_rn(cz, cz));
    int wcnt = 0;
    for (int g = 0; g < 16; ++g) {
      int n = wid * 1024 + g * 64 + lane;
      float x = xb[n];
      float y = xb[NPT + n];
      float z = xb[2 * NPT + n];
      float pn2 = __fadd_rn(__fadd_rn(__fmul_rn(x, x), __fmul_rn(y, y)),
                            __fmul_rn(z, z));
      float dot = fmaf(cz, z, fmaf(cy, y, __fmul_rn(cx, x)));
      float sqr = __fsub_rn(__fadd_rn(s2c, pn2), __fmul_rn(2.0f, dot));
      bool hit = !(sqr > R2);
      unsigned long long mm = __ballot(hit);
      int pos = wcnt + __popcll(mm & ((1ull << lane) - 1ull));
      if (hit && pos < NK) s_widx[wid][pos] = n;
      wcnt += __popcll(mm);
      if (wcnt >= NK) break;  // wave-uniform
    }
    if (lane == 0) s_wc[wid] = (wcnt < NK) ? wcnt : NK;
  }
  __syncthreads();

  if (t < NK) {
    int c0 = s_wc[0], c1 = s_wc[1], c2 = s_wc[2], c3 = s_wc[3];
    int total = c0 + c1 + c2 + c3;
    int cc[4] = {c0, c1, c2, c3};
    int p = (t < total) ? t : 0;  // pad misses with overall-first hit
    int w = 0;
    while (w < 3 && p >= cc[w]) { p -= cc[w]; ++w; }
    int n = s_widx[w][p];
    float gx = __fsub_rn(xb[n], cx);
    float gy = __fsub_rn(xb[NPT + n], cy);
    float gz = __fsub_rn(xb[2 * NPT + n], cz);
    gq[(size_t)bs * NK + t] = make_float4(gx, gy, gz, __int_as_float(n));
  }
}

// ---------------------------------------------------------------------------
// Kernel 4 (mega v5): unchanged from R10 (verified; ~320 us).
// ---------------------------------------------------------------------------
__global__ __launch_bounds__(MEGA_THREADS) void mega_kernel(
    const float* __restrict__ points, const float* __restrict__ ceA,
    const float4* __restrict__ gq,
    const float* __restrict__ w0, const float* __restrict__ b0,
    const float* __restrict__ g0, const float* __restrict__ be0,
    const float* __restrict__ m0, const float* __restrict__ v0,
    const float* __restrict__ w1, const float* __restrict__ b1,
    const float* __restrict__ g1, const float* __restrict__ be1,
    const float* __restrict__ m1, const float* __restrict__ v1,
    const float* __restrict__ w2, const float* __restrict__ b2,
    const float* __restrict__ g2, const float* __restrict__ be2,
    const float* __restrict__ m2, const float* __restrict__ v2,
    const float* __restrict__ a, float* __restrict__ out1) {
  extern __shared__ float lds[];
  float* s_a  = lds + OFF_A;
  float* s_w1 = lds + OFF_W1;
  float* s_w2 = lds + OFF_W2;
  float* s_w0 = lds + OFF_W0;
  float* s_h1 = lds + OFF_H1;
  float* s_h2 = lds + OFF_H2;
  float* s_u  = lds + OFF_U;

  const int t = threadIdx.x;
  const int k = t & 31;             // C-phase neighbor row
  const int g16 = t >> 5;           // C-phase oc group 0..15
  const int kk = t & 15;            // D/E/F k base (rows kk, kk+16)
  const int gg = t >> 4;            // D/E/F oc group 0..31

  // ---- stage weights into LDS (once per block) ----
  {
    const float4* srcA = (const float4*)a;
    float4* dstA = (float4*)s_a;
    for (int i = t; i < 4192; i += MEGA_THREADS) dstA[i] = srcA[i];
    const float4* src1 = (const float4*)w1;
    float4* dst1 = (float4*)s_w1;
    for (int i = t; i < 1024; i += MEGA_THREADS) dst1[i] = src1[i];
    const float4* src2 = (const float4*)w2;
    float4* dst2 = (float4*)s_w2;
    for (int i = t; i < 2048; i += MEGA_THREADS) dst2[i] = src2[i];
    for (int i = t; i < 576; i += MEGA_THREADS) s_w0[i] = w0[i];
  }
  __syncthreads();

  const int bs0 = blockIdx.x * QPB;

  float4 gv = gq[(size_t)bs0 * NK + k];
  float pts[6];
  {
    int n = __float_as_int(gv.w);
    const float* pb = points + (size_t)(bs0 >> 10) * DIN * NPT + n;
#pragma unroll
    for (int c = 0; c < 6; ++c) pts[c] = pb[(size_t)c * NPT];
  }

  for (int q = 0; q < QPB; ++q) {
    const int bs = bs0 + q;
    const int b = bs >> 10;
    const int s = bs & 1023;

    const int qn = (q + 1 < QPB) ? (q + 1) : q;
    const int bsn = bs0 + qn;
    float4 gv_next = gq[(size_t)bsn * NK + k];

    // ---- C: layer 1, 9 -> 64 (k = t&31, oc = g16*4 + j) ----
    {
      float in0[9];
      in0[0] = gv.x; in0[1] = gv.y; in0[2] = gv.z;
#pragma unroll
      for (int c = 0; c < 6; ++c) in0[3 + c] = pts[c];
      int oc0 = g16 * 4;
      float acc[4];
#pragma unroll
      for (int j = 0; j < 4; ++j) {
        float a0 = 0.f;
#pragma unroll
        for (int c = 0; c < 9; ++c)
          a0 = fmaf(in0[c], s_w0[(oc0 + j) * 9 + c], a0);
        acc[j] = bnrelu(a0, b0, g0, be0, m0, v0, oc0 + j);
      }
      *(float4*)&s_h1[k * 68 + oc0] = make_float4(acc[0], acc[1], acc[2], acc[3]);
    }
    __syncthreads();  // B1

    float pts_next[6];
    {
      int nn = __float_as_int(gv_next.w);
      const float* pbn = points + (size_t)(bsn >> 10) * DIN * NPT + nn;
#pragma unroll
      for (int c = 0; c < 6; ++c) pts_next[c] = pbn[(size_t)c * NPT];
    }

    // ---- D: layer 2, 64 -> 64; rows kk & kk+16, oc = gg*2 + j ----
    {
      int oc0 = gg * 2;
      float a0[2] = {0.f, 0.f}, a1[2] = {0.f, 0.f};
      const float4* row0 = (const float4*)&s_h1[kk * 68];
      const float4* row1 = (const float4*)&s_h1[(kk + 16) * 68];
#pragma unroll 4
      for (int c4 = 0; c4 < 16; ++c4) {
        float4 h0 = row0[c4];
        float4 h1 = row1[c4];
#pragma unroll
        for (int j = 0; j < 2; ++j) {
          float4 wv = *(const float4*)&s_w1[(oc0 + j) * 64 + c4 * 4];
          a0[j] = fmaf(h0.x, wv.x, a0[j]);
          a0[j] = fmaf(h0.y, wv.y, a0[j]);
          a0[j] = fmaf(h0.z, wv.z, a0[j]);
          a0[j] = fmaf(h0.w, wv.w, a0[j]);
          a1[j] = fmaf(h1.x, wv.x, a1[j]);
          a1[j] = fmaf(h1.y, wv.y, a1[j]);
          a1[j] = fmaf(h1.z, wv.z, a1[j]);
          a1[j] = fmaf(h1.w, wv.w, a1[j]);
        }
      }
#pragma unroll
      for (int j = 0; j < 2; ++j) {
        a0[j] = bnrelu(a0[j], b1, g1, be1, m1, v1, oc0 + j);
        a1[j] = bnrelu(a1[j], b1, g1, be1, m1, v1, oc0 + j);
      }
      s_h2[kk * 68 + oc0] = a0[0];
      s_h2[kk * 68 + oc0 + 1] = a0[1];
      s_h2[(kk + 16) * 68 + oc0] = a1[0];
      s_h2[(kk + 16) * 68 + oc0 + 1] = a1[1];
    }
    __syncthreads();  // B2

    // ---- E: layer 3, 64 -> 128; rows kk & kk+16, oc = gg*4 + j ----
    {
      int oc0 = gg * 4;
      float a0[4] = {0.f, 0.f, 0.f, 0.f}, a1[4] = {0.f, 0.f, 0.f, 0.f};
      const float4* row0 = (const float4*)&s_h2[kk * 68];
      const float4* row1 = (const float4*)&s_h2[(kk + 16) * 68];
#pragma unroll 4
      for (int c4 = 0; c4 < 16; ++c4) {
        float4 h0 = row0[c4];
        float4 h1 = row1[c4];
#pragma unroll
        for (int j = 0; j < 4; ++j) {
          float4 wv = *(const float4*)&s_w2[(oc0 + j) * 64 + c4 * 4];
          a0[j] = fmaf(h0.x, wv.x, a0[j]);
          a0[j] = fmaf(h0.y, wv.y, a0[j]);
          a0[j] = fmaf(h0.z, wv.z, a0[j]);
          a0[j] = fmaf(h0.w, wv.w, a0[j]);
          a1[j] = fmaf(h1.x, wv.x, a1[j]);
          a1[j] = fmaf(h1.y, wv.y, a1[j]);
          a1[j] = fmaf(h1.z, wv.z, a1[j]);
          a1[j] = fmaf(h1.w, wv.w, a1[j]);
        }
      }
#pragma unroll
      for (int j = 0; j < 4; ++j) {
        a0[j] = bnrelu(a0[j], b2, g2, be2, m2, v2, oc0 + j);
        a1[j] = bnrelu(a1[j], b2, g2, be2, m2, v2, oc0 + j);
      }
      *(float4*)&s_u[kk * 132 + oc0] = make_float4(a0[0], a0[1], a0[2], a0[3]);
      *(float4*)&s_u[(kk + 16) * 132 + oc0] =
          make_float4(a1[0], a1[1], a1[2], a1[3]);
      if (t < NK) {
        s_u[t * 132 + 128] = gv.x;
        s_u[t * 132 + 129] = gv.y;
        s_u[t * 132 + 130] = gv.z;
        s_u[t * 132 + 131] = 0.f;
      }
    }
    __syncthreads();  // B3

    // ---- F: attention; rows kk & kk+16, oc = gg*4 + j ----
    {
      int oc0 = gg * 4;
      float a0[4] = {0.f, 0.f, 0.f, 0.f}, a1[4] = {0.f, 0.f, 0.f, 0.f};
      const float4* urow0 = (const float4*)&s_u[kk * 132];
      const float4* urow1 = (const float4*)&s_u[(kk + 16) * 132];
      for (int r4 = 0; r4 < 33; ++r4) {
        float4 uv0 = urow0[r4];
        float4 uv1 = urow1[r4];
        int r = r4 * 4;
#pragma unroll
        for (int cc = 0; cc < 4; ++cc) {
          int rr = r + cc;
          int arow = (rr < 128) ? (rr + 3) : (rr - 128);  // rr==131 -> a[3]*0
          float uc0 = (cc == 0) ? uv0.x : (cc == 1) ? uv0.y : (cc == 2) ? uv0.z : uv0.w;
          float uc1 = (cc == 0) ? uv1.x : (cc == 1) ? uv1.y : (cc == 2) ? uv1.z : uv1.w;
          float4 av = *(const float4*)&s_a[arow * 128 + oc0];
          a0[0] = fmaf(uc0, av.x, a0[0]);
          a0[1] = fmaf(uc0, av.y, a0[1]);
          a0[2] = fmaf(uc0, av.z, a0[2]);
          a0[3] = fmaf(uc0, av.w, a0[3]);
          a1[0] = fmaf(uc1, av.x, a1[0]);
          a1[1] = fmaf(uc1, av.y, a1[1]);
          a1[2] = fmaf(uc1, av.z, a1[2]);
          a1[3] = fmaf(uc1, av.w, a1[3]);
        }
      }

      float4 cv = *(const float4*)&ceA[(size_t)bs * 128 + oc0];
      float4 h0v = *(const float4*)&s_u[kk * 132 + oc0];
      float4 h1v = *(const float4*)&s_u[(kk + 16) * 132 + oc0];
      float ce[4] = {cv.x, cv.y, cv.z, cv.w};
      float h0[4] = {h0v.x, h0v.y, h0v.z, h0v.w};
      float h1[4] = {h1v.x, h1v.y, h1v.z, h1v.w};

      float* outb = out1 + (size_t)b * 128 * NS + s;
#pragma unroll
      for (int j = 0; j < 4; ++j) {
        float e0 = ce[j] - a0[j];
        float e1 = ce[j] - a1[j];
        e0 = (e0 >= 0.f) ? e0 : 0.2f * e0;  // leaky relu alpha=0.2
        e1 = (e1 >= 0.f) ? e1 : 0.2f * e1;
        float mx = fmaxf(e0, e1);
#pragma unroll
        for (int off = 8; off > 0; off >>= 1)
          mx = fmaxf(mx, __shfl_xor(mx, off));   // stays in 16-lane group
        float p0 = expf(e0 - mx);
        float p1 = expf(e1 - mx);
        float num = p0 * h0[j] + p1 * h1[j];
        float den = p0 + p1;
#pragma unroll
        for (int off = 8; off > 0; off >>= 1) {
          num += __shfl_xor(num, off);
          den += __shfl_xor(den, off);
        }
        if (kk == 0) outb[(size_t)(oc0 + j) * NS] = num / den;
      }
    }
    // no trailing barrier needed (see R7 proof)

    gv = gv_next;
#pragma unroll
    for (int c = 0; c < 6; ++c) pts[c] = pts_next[c];
  }
}

// ---------------------------------------------------------------------------
extern "C" void kernel_launch(void* const* d_in, const int* in_sizes, int n_in,
                              void* d_out, int out_size, void* d_ws,
                              size_t ws_size, hipStream_t stream) {
  (void)in_sizes; (void)n_in; (void)out_size; (void)ws_size;
  const float* xyz = (const float*)d_in[0];
  const float* points = (const float*)d_in[1];
  const float* w0 = (const float*)d_in[2];
  const float* b0 = (const float*)d_in[3];
  const float* g0 = (const float*)d_in[4];
  const float* be0 = (const float*)d_in[5];
  const float* m0 = (const float*)d_in[6];
  const float* v0 = (const float*)d_in[7];
  const float* w1 = (const float*)d_in[8];
  const float* b1 = (const float*)d_in[9];
  const float* g1 = (const float*)d_in[10];
  const float* be1 = (const float*)d_in[11];
  const float* m1 = (const float*)d_in[12];
  const float* v1 = (const float*)d_in[13];
  const float* w2 = (const float*)d_in[14];
  const float* b2 = (const float*)d_in[15];
  const float* g2 = (const float*)d_in[16];
  const float* be2 = (const float*)d_in[17];
  const float* m2 = (const float*)d_in[18];
  const float* v2 = (const float*)d_in[19];
  const float* a = (const float*)d_in[20];

  float* out0 = (float*)d_out;                  // [B,3,S]
  float* out1 = out0 + (size_t)NB * 3 * NS;     // [B,128,S]

  int* fps = (int*)d_ws;                                        // 32 KB
  float* nxyz = (float*)((char*)d_ws + 32768);                  // 96 KB
  float* ceA = (float*)((char*)d_ws + 131072);                  // 4 MB
  float4* gq = (float4*)((char*)d_ws + 131072 + 4194304);       // 4 MB

  hipFuncSetAttribute(reinterpret_cast<const void*>(mega_kernel),
                      hipFuncAttributeMaxDynamicSharedMemorySize, SMEM_BYTES);

  fps_kernel<<<NB, 512, 0, stream>>>(xyz, fps, nxyz, out0);
  ballq_kernel<<<NB * NS, 256, 0, stream>>>(xyz, nxyz, gq);
  center_kernel<<<NB * NS, 64, 0, stream>>>(points, nxyz, fps,
      w0, b0, g0, be0, m0, v0, w1, b1, g1, be1, m1, v1,
      w2, b2, g2, be2, m2, v2, a, ceA);
  mega_kernel<<<NB * NS / QPB, MEGA_THREADS, SMEM_BYTES, stream>>>(
      points, ceA, gq,
      w0, b0, g0, be0, m0, v0, w1, b1, g1, be1, m1, v1,
      w2, b2, g2, be2, m2, v2, a, out1);
}

// Round 13
// 1131.665 us; speedup vs baseline: 1.1115x; 1.0089x over previous
//
#include <hip/hip_runtime.h>

#define NB  8
#define NPT 4096
#define NS  1024
#define NK  32
#define DIN 6
#define QPB 32          // queries per mega-block
#define MEGA_THREADS 512

// mega LDS float offsets
#define OFF_A   0            // 131*128 = 16768
#define OFF_W1  16768        // 64*64   = 4096
#define OFF_W2  20864        // 128*64  = 8192
#define OFF_W0  29056        // 64*9    = 576
#define OFF_H1  29632        // 32*68   = 2176
#define OFF_H2  31808        // 32*68   = 2176
#define OFF_U   33984        // 32*132  = 4224
#define FLT_TOT 38208
#define SMEM_BYTES (FLT_TOT * 4)   // 152832 B <= 160 KiB

// ---------------------------------------------------------------------------
__device__ __forceinline__ float bnrelu(float acc, const float* __restrict__ bb,
                                        const float* __restrict__ gg,
                                        const float* __restrict__ be,
                                        const float* __restrict__ mm,
                                        const float* __restrict__ vv, int oc) {
  float t = (acc + bb[oc]) - mm[oc];
  float val = gg[oc] * t * rsqrtf(vv[oc] + 1e-5f) + be[oc];
  return fmaxf(val, 0.0f);
}

// ---------------------------------------------------------------------------
// Wave64 max via DPP + readlane(63). Identity = -1.0f.
// ---------------------------------------------------------------------------
__device__ __forceinline__ float wave64_max(float x) {
  const int NEG1 = 0xbf800000;
  int v;
  v = __builtin_amdgcn_update_dpp(NEG1, __float_as_int(x), 0x111, 0xf, 0xf, false);
  x = fmaxf(x, __int_as_float(v));
  v = __builtin_amdgcn_update_dpp(NEG1, __float_as_int(x), 0x112, 0xf, 0xf, false);
  x = fmaxf(x, __int_as_float(v));
  v = __builtin_amdgcn_update_dpp(NEG1, __float_as_int(x), 0x114, 0xf, 0xf, false);
  x = fmaxf(x, __int_as_float(v));
  v = __builtin_amdgcn_update_dpp(NEG1, __float_as_int(x), 0x118, 0xf, 0xf, false);
  x = fmaxf(x, __int_as_float(v));
  v = __builtin_amdgcn_update_dpp(NEG1, __float_as_int(x), 0x142, 0xa, 0xf, false);
  x = fmaxf(x, __int_as_float(v));
  v = __builtin_amdgcn_update_dpp(NEG1, __float_as_int(x), 0x143, 0xc, 0xf, false);
  x = fmaxf(x, __int_as_float(v));
  return __int_as_float(__builtin_amdgcn_readlane(__float_as_int(x), 63));
}

// ---------------------------------------------------------------------------
// Kernel 1: FPS — exact verified v5 (512 thr x 8 pts, 660 us, VGPR 52).
// Five restructure attempts (1024-thr, 256-thr, tournament, pk-math, coords
// carry) were neutral or regressed; this structure is the keeper.
// ---------------------------------------------------------------------------
__global__ __launch_bounds__(512) void fps_kernel(const float* __restrict__ xyz,
                                                  int* __restrict__ fps_idx,
                                                  float* __restrict__ nxyz,
                                                  float* __restrict__ out0) {
  const int b = blockIdx.x;
  const int t = threadIdx.x;
  const int lane = t & 63, wid = t >> 6;
  const float* xb = xyz + (size_t)b * 3 * NPT;

  __shared__ float s_x[NPT], s_y[NPT], s_z[NPT];
  __shared__ __align__(16) float s_red[2][8][2];
  __shared__ float s_ox[NS], s_oy[NS], s_oz[NS];
  __shared__ int s_fi[NS];

  float px[8], py[8], pz[8], dist[8];
  const int base = t * 8;
#pragma unroll
  for (int j = 0; j < 8; ++j) {
    px[j] = xb[base + j];
    py[j] = xb[NPT + base + j];
    pz[j] = xb[2 * NPT + base + j];
    dist[j] = 1e10f;
  }
  for (int i = t; i < NPT; i += 512) {
    s_x[i] = xb[i];
    s_y[i] = xb[NPT + i];
    s_z[i] = xb[2 * NPT + i];
  }
  __syncthreads();

  int far = 0;
  float cx = xb[0], cy = xb[NPT], cz = xb[2 * NPT];

  for (int s = 0; s < NS; ++s) {
    if (t == 0) {
      s_ox[s] = cx; s_oy[s] = cy; s_oz[s] = cz; s_fi[s] = far;
    }
    float bv = -1.0f;
    int bi = 0;
#pragma unroll
    for (int j = 0; j < 8; ++j) {
      float dx = __fsub_rn(px[j], cx);
      float dy = __fsub_rn(py[j], cy);
      float dz = __fsub_rn(pz[j], cz);
      float d = __fadd_rn(__fadd_rn(__fmul_rn(dx, dx), __fmul_rn(dy, dy)),
                          __fmul_rn(dz, dz));
      float nd = fminf(dist[j], d);
      dist[j] = nd;
      bi = (nd > bv) ? (base + j) : bi;
      bv = fmaxf(bv, nd);
    }
    float mv = wave64_max(bv);
    unsigned long long mmask = __ballot(bv == mv);
    int src = __ffsll(mmask) - 1;
    int wi = __shfl(bi, src);

    const int p = s & 1;
    if (lane == 0) {
      s_red[p][wid][0] = mv;
      s_red[p][wid][1] = __int_as_float(wi);
    }
    __syncthreads();

    float4 q0 = *(const float4*)&s_red[p][0][0];
    float4 q1 = *(const float4*)&s_red[p][2][0];
    float4 q2 = *(const float4*)&s_red[p][4][0];
    float4 q3 = *(const float4*)&s_red[p][6][0];
    // tournament: right side wins only on strict > => first max overall
    float va, vb, vc, vd; int ia, ib, ic, id;
    { bool g = q0.z > q0.x; va = g ? q0.z : q0.x;
      ia = g ? __float_as_int(q0.w) : __float_as_int(q0.y); }
    { bool g = q1.z > q1.x; vb = g ? q1.z : q1.x;
      ib = g ? __float_as_int(q1.w) : __float_as_int(q1.y); }
    { bool g = q2.z > q2.x; vc = g ? q2.z : q2.x;
      ic = g ? __float_as_int(q2.w) : __float_as_int(q2.y); }
    { bool g = q3.z > q3.x; vd = g ? q3.z : q3.x;
      id = g ? __float_as_int(q3.w) : __float_as_int(q3.y); }
    { bool g = vb > va; va = g ? vb : va; ia = g ? ib : ia; }
    { bool g = vd > vc; vc = g ? vd : vc; ic = g ? id : ic; }
    { bool g = vc > va; va = g ? vc : va; ia = g ? ic : ia; }
    far = ia;
    cx = s_x[far]; cy = s_y[far]; cz = s_z[far];
  }

  __syncthreads();
  for (int i = t; i < NS; i += 512) {
    float X = s_ox[i], Y = s_oy[i], Z = s_oz[i];
    out0[((size_t)b * 3 + 0) * NS + i] = X;
    out0[((size_t)b * 3 + 1) * NS + i] = Y;
    out0[((size_t)b * 3 + 2) * NS + i] = Z;
    nxyz[((size_t)b * NS + i) * 3 + 0] = X;
    nxyz[((size_t)b * NS + i) * 3 + 1] = Y;
    nxyz[((size_t)b * NS + i) * 3 + 2] = Z;
    fps_idx[b * NS + i] = s_fi[i];
  }
}

// ---------------------------------------------------------------------------
// Kernel 2 (fused): ball query + gather + center MLP + ceA. One 256-thread
// block per query. Ballq phase identical to the verified standalone; center
// phases use t<64 (L1/L2, identical FMA order) and t<128 (L3/ceA, 1 oc per
// thread, same ascending-c order -> bit-exact vs verified center_kernel).
// Kills 8192 tiny 64-thread center blocks + one launch.
// ---------------------------------------------------------------------------
__global__ __launch_bounds__(256) void ballq_center_kernel(
    const float* __restrict__ xyz, const float* __restrict__ points,
    const float* __restrict__ nxyz, const int* __restrict__ fps_idx,
    const float* __restrict__ w0, const float* __restrict__ b0,
    const float* __restrict__ g0, const float* __restrict__ be0,
    const float* __restrict__ m0, const float* __restrict__ v0,
    const float* __restrict__ w1, const float* __restrict__ b1,
    const float* __restrict__ g1, const float* __restrict__ be1,
    const float* __restrict__ m1, const float* __restrict__ v1,
    const float* __restrict__ w2, const float* __restrict__ b2,
    const float* __restrict__ g2, const float* __restrict__ be2,
    const float* __restrict__ m2, const float* __restrict__ v2,
    const float* __restrict__ a, float4* __restrict__ gq,
    float* __restrict__ ceA) {
  const int bs = blockIdx.x;
  const int b = bs >> 10;
  const int t = threadIdx.x;
  const int lane = t & 63;
  const int wid = t >> 6;

  __shared__ int s_widx[4][NK];
  __shared__ int s_wc[4];
  __shared__ float ci[9];
  __shared__ float ch1[64];
  __shared__ float ch2[64];
  __shared__ float ch3[128];

  const float* xb = xyz + (size_t)b * 3 * NPT;
  const float cx = nxyz[(size_t)bs * 3 + 0];
  const float cy = nxyz[(size_t)bs * 3 + 1];
  const float cz = nxyz[(size_t)bs * 3 + 2];

  // ---- ball query scan: each wave scans its contiguous 1024-point quarter --
  {
    const float R2 = (float)(0.15 * 0.15);
    float s2c = __fadd_rn(__fadd_rn(__fmul_rn(cx, cx), __fmul_rn(cy, cy)),
                          __fmul_rn(cz, cz));
    int wcnt = 0;
    for (int g = 0; g < 16; ++g) {
      int n = wid * 1024 + g * 64 + lane;
      float x = xb[n];
      float y = xb[NPT + n];
      float z = xb[2 * NPT + n];
      float pn2 = __fadd_rn(__fadd_rn(__fmul_rn(x, x), __fmul_rn(y, y)),
                            __fmul_rn(z, z));
      float dot = fmaf(cz, z, fmaf(cy, y, __fmul_rn(cx, x)));
      float sqr = __fsub_rn(__fadd_rn(s2c, pn2), __fmul_rn(2.0f, dot));
      bool hit = !(sqr > R2);
      unsigned long long mm = __ballot(hit);
      int pos = wcnt + __popcll(mm & ((1ull << lane) - 1ull));
      if (hit && pos < NK) s_widx[wid][pos] = n;
      wcnt += __popcll(mm);
      if (wcnt >= NK) break;  // wave-uniform
    }
    if (lane == 0) s_wc[wid] = (wcnt < NK) ? wcnt : NK;
  }
  // load center input while the scan results settle (independent of ballq)
  if (t < 9) {
    ci[t] = (t < 3) ? nxyz[(size_t)bs * 3 + t]
                    : points[((size_t)b * DIN + (t - 3)) * NPT + fps_idx[bs]];
  }
  __syncthreads();

  // ---- merge per-wave lists in ascending index order; write gq ----
  if (t < NK) {
    int c0 = s_wc[0], c1 = s_wc[1], c2 = s_wc[2], c3 = s_wc[3];
    int total = c0 + c1 + c2 + c3;
    int cc[4] = {c0, c1, c2, c3};
    int p = (t < total) ? t : 0;  // pad misses with overall-first hit
    int w = 0;
    while (w < 3 && p >= cc[w]) { p -= cc[w]; ++w; }
    int n = s_widx[w][p];
    float gx = __fsub_rn(xb[n], cx);
    float gy = __fsub_rn(xb[NPT + n], cy);
    float gz = __fsub_rn(xb[2 * NPT + n], cz);
    gq[(size_t)bs * NK + t] = make_float4(gx, gy, gz, __int_as_float(n));
  }

  // ---- center MLP (bit-exact port of verified center_kernel) ----
  if (t < 64) {
    float acc = 0.f;
#pragma unroll
    for (int c = 0; c < 9; ++c) acc = fmaf(ci[c], w0[t * 9 + c], acc);
    ch1[t] = bnrelu(acc, b0, g0, be0, m0, v0, t);
  }
  __syncthreads();
  if (t < 64) {
    float acc = 0.f;
#pragma unroll 8
    for (int c = 0; c < 64; ++c) acc = fmaf(ch1[c], w1[t * 64 + c], acc);
    ch2[t] = bnrelu(acc, b1, g1, be1, m1, v1, t);
  }
  __syncthreads();
  if (t < 128) {
    float acc = 0.f;
#pragma unroll 8
    for (int c = 0; c < 64; ++c) acc = fmaf(ch2[c], w2[t * 64 + c], acc);
    ch3[t] = bnrelu(acc, b2, g2, be2, m2, v2, t);
  }
  __syncthreads();
  if (t < 128) {
    float acc = 0.f;
#pragma unroll 8
    for (int c = 0; c < 128; ++c) acc = fmaf(ch3[c], a[(3 + c) * 128 + t], acc);
    ceA[(size_t)bs * 128 + t] = acc;
  }
}

// ---------------------------------------------------------------------------
// Kernel 3 (mega v5): unchanged from R10 (verified; ~320 us).
// ---------------------------------------------------------------------------
__global__ __launch_bounds__(MEGA_THREADS) void mega_kernel(
    const float* __restrict__ points, const float* __restrict__ ceA,
    const float4* __restrict__ gq,
    const float* __restrict__ w0, const float* __restrict__ b0,
    const float* __restrict__ g0, const float* __restrict__ be0,
    const float* __restrict__ m0, const float* __restrict__ v0,
    const float* __restrict__ w1, const float* __restrict__ b1,
    const float* __restrict__ g1, const float* __restrict__ be1,
    const float* __restrict__ m1, const float* __restrict__ v1,
    const float* __restrict__ w2, const float* __restrict__ b2,
    const float* __restrict__ g2, const float* __restrict__ be2,
    const float* __restrict__ m2, const float* __restrict__ v2,
    const float* __restrict__ a, float* __restrict__ out1) {
  extern __shared__ float lds[];
  float* s_a  = lds + OFF_A;
  float* s_w1 = lds + OFF_W1;
  float* s_w2 = lds + OFF_W2;
  float* s_w0 = lds + OFF_W0;
  float* s_h1 = lds + OFF_H1;
  float* s_h2 = lds + OFF_H2;
  float* s_u  = lds + OFF_U;

  const int t = threadIdx.x;
  const int k = t & 31;             // C-phase neighbor row
  const int g16 = t >> 5;           // C-phase oc group 0..15
  const int kk = t & 15;            // D/E/F k base (rows kk, kk+16)
  const int gg = t >> 4;            // D/E/F oc group 0..31

  // ---- stage weights into LDS (once per block) ----
  {
    const float4* srcA = (const float4*)a;
    float4* dstA = (float4*)s_a;
    for (int i = t; i < 4192; i += MEGA_THREADS) dstA[i] = srcA[i];
    const float4* src1 = (const float4*)w1;
    float4* dst1 = (float4*)s_w1;
    for (int i = t; i < 1024; i += MEGA_THREADS) dst1[i] = src1[i];
    const float4* src2 = (const float4*)w2;
    float4* dst2 = (float4*)s_w2;
    for (int i = t; i < 2048; i += MEGA_THREADS) dst2[i] = src2[i];
    for (int i = t; i < 576; i += MEGA_THREADS) s_w0[i] = w0[i];
  }
  __syncthreads();

  const int bs0 = blockIdx.x * QPB;

  float4 gv = gq[(size_t)bs0 * NK + k];
  float pts[6];
  {
    int n = __float_as_int(gv.w);
    const float* pb = points + (size_t)(bs0 >> 10) * DIN * NPT + n;
#pragma unroll
    for (int c = 0; c < 6; ++c) pts[c] = pb[(size_t)c * NPT];
  }

  for (int q = 0; q < QPB; ++q) {
    const int bs = bs0 + q;
    const int b = bs >> 10;
    const int s = bs & 1023;

    const int qn = (q + 1 < QPB) ? (q + 1) : q;
    const int bsn = bs0 + qn;
    float4 gv_next = gq[(size_t)bsn * NK + k];

    // ---- C: layer 1, 9 -> 64 (k = t&31, oc = g16*4 + j) ----
    {
      float in0[9];
      in0[0] = gv.x; in0[1] = gv.y; in0[2] = gv.z;
#pragma unroll
      for (int c = 0; c < 6; ++c) in0[3 + c] = pts[c];
      int oc0 = g16 * 4;
      float acc[4];
#pragma unroll
      for (int j = 0; j < 4; ++j) {
        float a0 = 0.f;
#pragma unroll
        for (int c = 0; c < 9; ++c)
          a0 = fmaf(in0[c], s_w0[(oc0 + j) * 9 + c], a0);
        acc[j] = bnrelu(a0, b0, g0, be0, m0, v0, oc0 + j);
      }
      *(float4*)&s_h1[k * 68 + oc0] = make_float4(acc[0], acc[1], acc[2], acc[3]);
    }
    __syncthreads();  // B1

    float pts_next[6];
    {
      int nn = __float_as_int(gv_next.w);
      const float* pbn = points + (size_t)(bsn >> 10) * DIN * NPT + nn;
#pragma unroll
      for (int c = 0; c < 6; ++c) pts_next[c] = pbn[(size_t)c * NPT];
    }

    // ---- D: layer 2, 64 -> 64; rows kk & kk+16, oc = gg*2 + j ----
    {
      int oc0 = gg * 2;
      float a0[2] = {0.f, 0.f}, a1[2] = {0.f, 0.f};
      const float4* row0 = (const float4*)&s_h1[kk * 68];
      const float4* row1 = (const float4*)&s_h1[(kk + 16) * 68];
#pragma unroll 4
      for (int c4 = 0; c4 < 16; ++c4) {
        float4 h0 = row0[c4];
        float4 h1 = row1[c4];
#pragma unroll
        for (int j = 0; j < 2; ++j) {
          float4 wv = *(const float4*)&s_w1[(oc0 + j) * 64 + c4 * 4];
          a0[j] = fmaf(h0.x, wv.x, a0[j]);
          a0[j] = fmaf(h0.y, wv.y, a0[j]);
          a0[j] = fmaf(h0.z, wv.z, a0[j]);
          a0[j] = fmaf(h0.w, wv.w, a0[j]);
          a1[j] = fmaf(h1.x, wv.x, a1[j]);
          a1[j] = fmaf(h1.y, wv.y, a1[j]);
          a1[j] = fmaf(h1.z, wv.z, a1[j]);
          a1[j] = fmaf(h1.w, wv.w, a1[j]);
        }
      }
#pragma unroll
      for (int j = 0; j < 2; ++j) {
        a0[j] = bnrelu(a0[j], b1, g1, be1, m1, v1, oc0 + j);
        a1[j] = bnrelu(a1[j], b1, g1, be1, m1, v1, oc0 + j);
      }
      s_h2[kk * 68 + oc0] = a0[0];
      s_h2[kk * 68 + oc0 + 1] = a0[1];
      s_h2[(kk + 16) * 68 + oc0] = a1[0];
      s_h2[(kk + 16) * 68 + oc0 + 1] = a1[1];
    }
    __syncthreads();  // B2

    // ---- E: layer 3, 64 -> 128; rows kk & kk+16, oc = gg*4 + j ----
    {
      int oc0 = gg * 4;
      float a0[4] = {0.f, 0.f, 0.f, 0.f}, a1[4] = {0.f, 0.f, 0.f, 0.f};
      const float4* row0 = (const float4*)&s_h2[kk * 68];
      const float4* row1 = (const float4*)&s_h2[(kk + 16) * 68];
#pragma unroll 4
      for (int c4 = 0; c4 < 16; ++c4) {
        float4 h0 = row0[c4];
        float4 h1 = row1[c4];
#pragma unroll
        for (int j = 0; j < 4; ++j) {
          float4 wv = *(const float4*)&s_w2[(oc0 + j) * 64 + c4 * 4];
          a0[j] = fmaf(h0.x, wv.x, a0[j]);
          a0[j] = fmaf(h0.y, wv.y, a0[j]);
          a0[j] = fmaf(h0.z, wv.z, a0[j]);
          a0[j] = fmaf(h0.w, wv.w, a0[j]);
          a1[j] = fmaf(h1.x, wv.x, a1[j]);
          a1[j] = fmaf(h1.y, wv.y, a1[j]);
          a1[j] = fmaf(h1.z, wv.z, a1[j]);
          a1[j] = fmaf(h1.w, wv.w, a1[j]);
        }
      }
#pragma unroll
      for (int j = 0; j < 4; ++j) {
        a0[j] = bnrelu(a0[j], b2, g2, be2, m2, v2, oc0 + j);
        a1[j] = bnrelu(a1[j], b2, g2, be2, m2, v2, oc0 + j);
      }
      *(float4*)&s_u[kk * 132 + oc0] = make_float4(a0[0], a0[1], a0[2], a0[3]);
      *(float4*)&s_u[(kk + 16) * 132 + oc0] =
          make_float4(a1[0], a1[1], a1[2], a1[3]);
      if (t < NK) {
        s_u[t * 132 + 128] = gv.x;
        s_u[t * 132 + 129] = gv.y;
        s_u[t * 132 + 130] = gv.z;
        s_u[t * 132 + 131] = 0.f;
      }
    }
    __syncthreads();  // B3

    // ---- F: attention; rows kk & kk+16, oc = gg*4 + j ----
    {
      int oc0 = gg * 4;
      float a0[4] = {0.f, 0.f, 0.f, 0.f}, a1[4] = {0.f, 0.f, 0.f, 0.f};
      const float4* urow0 = (const float4*)&s_u[kk * 132];
      const float4* urow1 = (const float4*)&s_u[(kk + 16) * 132];
      for (int r4 = 0; r4 < 33; ++r4) {
        float4 uv0 = urow0[r4];
        float4 uv1 = urow1[r4];
        int r = r4 * 4;
#pragma unroll
        for (int cc = 0; cc < 4; ++cc) {
          int rr = r + cc;
          int arow = (rr < 128) ? (rr + 3) : (rr - 128);  // rr==131 -> a[3]*0
          float uc0 = (cc == 0) ? uv0.x : (cc == 1) ? uv0.y : (cc == 2) ? uv0.z : uv0.w;
          float uc1 = (cc == 0) ? uv1.x : (cc == 1) ? uv1.y : (cc == 2) ? uv1.z : uv1.w;
          float4 av = *(const float4*)&s_a[arow * 128 + oc0];
          a0[0] = fmaf(uc0, av.x, a0[0]);
          a0[1] = fmaf(uc0, av.y, a0[1]);
          a0[2] = fmaf(uc0, av.z, a0[2]);
          a0[3] = fmaf(uc0, av.w, a0[3]);
          a1[0] = fmaf(uc1, av.x, a1[0]);
          a1[1] = fmaf(uc1, av.y, a1[1]);
          a1[2] = fmaf(uc1, av.z, a1[2]);
          a1[3] = fmaf(uc1, av.w, a1[3]);
        }
      }

      float4 cv = *(const float4*)&ceA[(size_t)bs * 128 + oc0];
      float4 h0v = *(const float4*)&s_u[kk * 132 + oc0];
      float4 h1v = *(const float4*)&s_u[(kk + 16) * 132 + oc0];
      float ce[4] = {cv.x, cv.y, cv.z, cv.w};
      float h0[4] = {h0v.x, h0v.y, h0v.z, h0v.w};
      float h1[4] = {h1v.x, h1v.y, h1v.z, h1v.w};

      float* outb = out1 + (size_t)b * 128 * NS + s;
#pragma unroll
      for (int j = 0; j < 4; ++j) {
        float e0 = ce[j] - a0[j];
        float e1 = ce[j] - a1[j];
        e0 = (e0 >= 0.f) ? e0 : 0.2f * e0;  // leaky relu alpha=0.2
        e1 = (e1 >= 0.f) ? e1 : 0.2f * e1;
        float mx = fmaxf(e0, e1);
#pragma unroll
        for (int off = 8; off > 0; off >>= 1)
          mx = fmaxf(mx, __shfl_xor(mx, off));   // stays in 16-lane group
        float p0 = expf(e0 - mx);
        float p1 = expf(e1 - mx);
        float num = p0 * h0[j] + p1 * h1[j];
        float den = p0 + p1;
#pragma unroll
        for (int off = 8; off > 0; off >>= 1) {
          num += __shfl_xor(num, off);
          den += __shfl_xor(den, off);
        }
        if (kk == 0) outb[(size_t)(oc0 + j) * NS] = num / den;
      }
    }
    // no trailing barrier needed (see R7 proof)

    gv = gv_next;
#pragma unroll
    for (int c = 0; c < 6; ++c) pts[c] = pts_next[c];
  }
}

// ---------------------------------------------------------------------------
extern "C" void kernel_launch(void* const* d_in, const int* in_sizes, int n_in,
                              void* d_out, int out_size, void* d_ws,
                              size_t ws_size, hipStream_t stream) {
  (void)in_sizes; (void)n_in; (void)out_size; (void)ws_size;
  const float* xyz = (const float*)d_in[0];
  const float* points = (const float*)d_in[1];
  const float* w0 = (const float*)d_in[2];
  const float* b0 = (const float*)d_in[3];
  const float* g0 = (const float*)d_in[4];
  const float* be0 = (const float*)d_in[5];
  const float* m0 = (const float*)d_in[6];
  const float* v0 = (const float*)d_in[7];
  const float* w1 = (const float*)d_in[8];
  const float* b1 = (const float*)d_in[9];
  const float* g1 = (const float*)d_in[10];
  const float* be1 = (const float*)d_in[11];
  const float* m1 = (const float*)d_in[12];
  const float* v1 = (const float*)d_in[13];
  const float* w2 = (const float*)d_in[14];
  const float* b2 = (const float*)d_in[15];
  const float* g2 = (const float*)d_in[16];
  const float* be2 = (const float*)d_in[17];
  const float* m2 = (const float*)d_in[18];
  const float* v2 = (const float*)d_in[19];
  const float* a = (const float*)d_in[20];

  float* out0 = (float*)d_out;                  // [B,3,S]
  float* out1 = out0 + (size_t)NB * 3 * NS;     // [B,128,S]

  int* fps = (int*)d_ws;                                        // 32 KB
  float* nxyz = (float*)((char*)d_ws + 32768);                  // 96 KB
  float* ceA = (float*)((char*)d_ws + 131072);                  // 4 MB
  float4* gq = (float4*)((char*)d_ws + 131072 + 4194304);       // 4 MB

  hipFuncSetAttribute(reinterpret_cast<const void*>(mega_kernel),
                      hipFuncAttributeMaxDynamicSharedMemorySize, SMEM_BYTES);

  fps_kernel<<<NB, 512, 0, stream>>>(xyz, fps, nxyz, out0);
  ballq_center_kernel<<<NB * NS, 256, 0, stream>>>(xyz, points, nxyz, fps,
      w0, b0, g0, be0, m0, v0, w1, b1, g1, be1, m1, v1,
      w2, b2, g2, be2, m2, v2, a, gq, ceA);
  mega_kernel<<<NB * NS / QPB, MEGA_THREADS, SMEM_BYTES, stream>>>(
      points, ceA, gq,
      w0, b0, g0, be0, m0, v0, w1, b1, g1, be1, m1, v1,
      w2, b2, g2, be2, m2, v2, a, out1);
}

// Round 14
// 1128.393 us; speedup vs baseline: 1.1147x; 1.0029x over previous
//
#include <hip/hip_runtime.h>

#define NB  8
#define NPT 4096
#define NS  1024
#define NK  32
#define DIN 6
#define QPB 32          // queries per mega-block
#define MEGA_THREADS 512

// mega LDS float offsets
#define OFF_A   0            // 131*128 = 16768
#define OFF_W1  16768        // 64*64   = 4096
#define OFF_W2  20864        // 128*64  = 8192
#define OFF_W0  29056        // 64*9    = 576
#define OFF_H1  29632        // 32*68   = 2176
#define OFF_H2  31808        // 32*68   = 2176
#define OFF_U   33984        // 32*132  = 4224
#define FLT_TOT 38208
#define SMEM_BYTES (FLT_TOT * 4)   // 152832 B <= 160 KiB

// ---------------------------------------------------------------------------
__device__ __forceinline__ float bnrelu(float acc, const float* __restrict__ bb,
                                        const float* __restrict__ gg,
                                        const float* __restrict__ be,
                                        const float* __restrict__ mm,
                                        const float* __restrict__ vv, int oc) {
  float t = (acc + bb[oc]) - mm[oc];
  float val = gg[oc] * t * rsqrtf(vv[oc] + 1e-5f) + be[oc];
  return fmaxf(val, 0.0f);
}

// ---------------------------------------------------------------------------
// Wave64 max via DPP + readlane(63). Identity = -1.0f.
// ---------------------------------------------------------------------------
__device__ __forceinline__ float wave64_max(float x) {
  const int NEG1 = 0xbf800000;
  int v;
  v = __builtin_amdgcn_update_dpp(NEG1, __float_as_int(x), 0x111, 0xf, 0xf, false);
  x = fmaxf(x, __int_as_float(v));
  v = __builtin_amdgcn_update_dpp(NEG1, __float_as_int(x), 0x112, 0xf, 0xf, false);
  x = fmaxf(x, __int_as_float(v));
  v = __builtin_amdgcn_update_dpp(NEG1, __float_as_int(x), 0x114, 0xf, 0xf, false);
  x = fmaxf(x, __int_as_float(v));
  v = __builtin_amdgcn_update_dpp(NEG1, __float_as_int(x), 0x118, 0xf, 0xf, false);
  x = fmaxf(x, __int_as_float(v));
  v = __builtin_amdgcn_update_dpp(NEG1, __float_as_int(x), 0x142, 0xa, 0xf, false);
  x = fmaxf(x, __int_as_float(v));
  v = __builtin_amdgcn_update_dpp(NEG1, __float_as_int(x), 0x143, 0xc, 0xf, false);
  x = fmaxf(x, __int_as_float(v));
  return __int_as_float(__builtin_amdgcn_readlane(__float_as_int(x), 63));
}

// ---------------------------------------------------------------------------
// Kernel 1: FPS — exact verified v5 (512 thr x 8 pts, 660 us, VGPR 52).
// ---------------------------------------------------------------------------
__global__ __launch_bounds__(512) void fps_kernel(const float* __restrict__ xyz,
                                                  int* __restrict__ fps_idx,
                                                  float* __restrict__ nxyz,
                                                  float* __restrict__ out0) {
  const int b = blockIdx.x;
  const int t = threadIdx.x;
  const int lane = t & 63, wid = t >> 6;
  const float* xb = xyz + (size_t)b * 3 * NPT;

  __shared__ float s_x[NPT], s_y[NPT], s_z[NPT];
  __shared__ __align__(16) float s_red[2][8][2];
  __shared__ float s_ox[NS], s_oy[NS], s_oz[NS];
  __shared__ int s_fi[NS];

  float px[8], py[8], pz[8], dist[8];
  const int base = t * 8;
#pragma unroll
  for (int j = 0; j < 8; ++j) {
    px[j] = xb[base + j];
    py[j] = xb[NPT + base + j];
    pz[j] = xb[2 * NPT + base + j];
    dist[j] = 1e10f;
  }
  for (int i = t; i < NPT; i += 512) {
    s_x[i] = xb[i];
    s_y[i] = xb[NPT + i];
    s_z[i] = xb[2 * NPT + i];
  }
  __syncthreads();

  int far = 0;
  float cx = xb[0], cy = xb[NPT], cz = xb[2 * NPT];

  for (int s = 0; s < NS; ++s) {
    if (t == 0) {
      s_ox[s] = cx; s_oy[s] = cy; s_oz[s] = cz; s_fi[s] = far;
    }
    float bv = -1.0f;
    int bi = 0;
#pragma unroll
    for (int j = 0; j < 8; ++j) {
      float dx = __fsub_rn(px[j], cx);
      float dy = __fsub_rn(py[j], cy);
      float dz = __fsub_rn(pz[j], cz);
      float d = __fadd_rn(__fadd_rn(__fmul_rn(dx, dx), __fmul_rn(dy, dy)),
                          __fmul_rn(dz, dz));
      float nd = fminf(dist[j], d);
      dist[j] = nd;
      bi = (nd > bv) ? (base + j) : bi;
      bv = fmaxf(bv, nd);
    }
    float mv = wave64_max(bv);
    unsigned long long mmask = __ballot(bv == mv);
    int src = __ffsll(mmask) - 1;
    int wi = __shfl(bi, src);

    const int p = s & 1;
    if (lane == 0) {
      s_red[p][wid][0] = mv;
      s_red[p][wid][1] = __int_as_float(wi);
    }
    __syncthreads();

    float4 q0 = *(const float4*)&s_red[p][0][0];
    float4 q1 = *(const float4*)&s_red[p][2][0];
    float4 q2 = *(const float4*)&s_red[p][4][0];
    float4 q3 = *(const float4*)&s_red[p][6][0];
    // tournament: right side wins only on strict > => first max overall
    float va, vb, vc, vd; int ia, ib, ic, id;
    { bool g = q0.z > q0.x; va = g ? q0.z : q0.x;
      ia = g ? __float_as_int(q0.w) : __float_as_int(q0.y); }
    { bool g = q1.z > q1.x; vb = g ? q1.z : q1.x;
      ib = g ? __float_as_int(q1.w) : __float_as_int(q1.y); }
    { bool g = q2.z > q2.x; vc = g ? q2.z : q2.x;
      ic = g ? __float_as_int(q2.w) : __float_as_int(q2.y); }
    { bool g = q3.z > q3.x; vd = g ? q3.z : q3.x;
      id = g ? __float_as_int(q3.w) : __float_as_int(q3.y); }
    { bool g = vb > va; va = g ? vb : va; ia = g ? ib : ia; }
    { bool g = vd > vc; vc = g ? vd : vc; ic = g ? id : ic; }
    { bool g = vc > va; va = g ? vc : va; ia = g ? ic : ia; }
    far = ia;
    cx = s_x[far]; cy = s_y[far]; cz = s_z[far];
  }

  __syncthreads();
  for (int i = t; i < NS; i += 512) {
    float X = s_ox[i], Y = s_oy[i], Z = s_oz[i];
    out0[((size_t)b * 3 + 0) * NS + i] = X;
    out0[((size_t)b * 3 + 1) * NS + i] = Y;
    out0[((size_t)b * 3 + 2) * NS + i] = Z;
    nxyz[((size_t)b * NS + i) * 3 + 0] = X;
    nxyz[((size_t)b * NS + i) * 3 + 1] = Y;
    nxyz[((size_t)b * NS + i) * 3 + 2] = Z;
    fps_idx[b * NS + i] = s_fi[i];
  }
}

// ---------------------------------------------------------------------------
// Kernel 2 (fused): ball query + gather + center MLP + ceA.
// v2: the scan's early-break is removed and all 48 chunk loads are issued
// UP FRONT (preload phase) -- the break made chunk g+1's loads wait on
// chunk g's ballot (~16 x 300 cy serial L2 chains). Ballot math, ascending
// chunk order, pos/wcnt semantics identical: lanes with pos >= NK never
// wrote anyway, and s_wc caps at NK either way.
// ---------------------------------------------------------------------------
__global__ __launch_bounds__(256) void ballq_center_kernel(
    const float* __restrict__ xyz, const float* __restrict__ points,
    const float* __restrict__ nxyz, const int* __restrict__ fps_idx,
    const float* __restrict__ w0, const float* __restrict__ b0,
    const float* __restrict__ g0, const float* __restrict__ be0,
    const float* __restrict__ m0, const float* __restrict__ v0,
    const float* __restrict__ w1, const float* __restrict__ b1,
    const float* __restrict__ g1, const float* __restrict__ be1,
    const float* __restrict__ m1, const float* __restrict__ v1,
    const float* __restrict__ w2, const float* __restrict__ b2,
    const float* __restrict__ g2, const float* __restrict__ be2,
    const float* __restrict__ m2, const float* __restrict__ v2,
    const float* __restrict__ a, float4* __restrict__ gq,
    float* __restrict__ ceA) {
  const int bs = blockIdx.x;
  const int b = bs >> 10;
  const int t = threadIdx.x;
  const int lane = t & 63;
  const int wid = t >> 6;

  __shared__ int s_widx[4][NK];
  __shared__ int s_wc[4];
  __shared__ float ci[9];
  __shared__ float ch1[64];
  __shared__ float ch2[64];
  __shared__ float ch3[128];

  const float* xb = xyz + (size_t)b * 3 * NPT;
  const float cx = nxyz[(size_t)bs * 3 + 0];
  const float cy = nxyz[(size_t)bs * 3 + 1];
  const float cz = nxyz[(size_t)bs * 3 + 2];

  // ---- ball query: preload all 16 chunks (48 loads in flight), then scan --
  {
    const float R2 = (float)(0.15 * 0.15);
    float s2c = __fadd_rn(__fadd_rn(__fmul_rn(cx, cx), __fmul_rn(cy, cy)),
                          __fmul_rn(cz, cz));
    float lx[16], ly[16], lz[16];
#pragma unroll
    for (int g = 0; g < 16; ++g) {
      int n = wid * 1024 + g * 64 + lane;
      lx[g] = xb[n];
      ly[g] = xb[NPT + n];
      lz[g] = xb[2 * NPT + n];
    }
    int wcnt = 0;
#pragma unroll
    for (int g = 0; g < 16; ++g) {
      int n = wid * 1024 + g * 64 + lane;
      float x = lx[g], y = ly[g], z = lz[g];
      float pn2 = __fadd_rn(__fadd_rn(__fmul_rn(x, x), __fmul_rn(y, y)),
                            __fmul_rn(z, z));
      float dot = fmaf(cz, z, fmaf(cy, y, __fmul_rn(cx, x)));
      float sqr = __fsub_rn(__fadd_rn(s2c, pn2), __fmul_rn(2.0f, dot));
      bool hit = !(sqr > R2);
      unsigned long long mm = __ballot(hit);
      int pos = wcnt + __popcll(mm & ((1ull << lane) - 1ull));
      if (hit && pos < NK) s_widx[wid][pos] = n;
      wcnt += __popcll(mm);
    }
    if (lane == 0) s_wc[wid] = (wcnt < NK) ? wcnt : NK;
  }
  // load center input (independent of ballq)
  if (t < 9) {
    ci[t] = (t < 3) ? nxyz[(size_t)bs * 3 + t]
                    : points[((size_t)b * DIN + (t - 3)) * NPT + fps_idx[bs]];
  }
  __syncthreads();

  // ---- merge per-wave lists in ascending index order; write gq ----
  if (t < NK) {
    int c0 = s_wc[0], c1 = s_wc[1], c2 = s_wc[2], c3 = s_wc[3];
    int total = c0 + c1 + c2 + c3;
    int cc[4] = {c0, c1, c2, c3};
    int p = (t < total) ? t : 0;  // pad misses with overall-first hit
    int w = 0;
    while (w < 3 && p >= cc[w]) { p -= cc[w]; ++w; }
    int n = s_widx[w][p];
    float gx = __fsub_rn(xb[n], cx);
    float gy = __fsub_rn(xb[NPT + n], cy);
    float gz = __fsub_rn(xb[2 * NPT + n], cz);
    gq[(size_t)bs * NK + t] = make_float4(gx, gy, gz, __int_as_float(n));
  }

  // ---- center MLP (bit-exact port of verified center_kernel) ----
  if (t < 64) {
    float acc = 0.f;
#pragma unroll
    for (int c = 0; c < 9; ++c) acc = fmaf(ci[c], w0[t * 9 + c], acc);
    ch1[t] = bnrelu(acc, b0, g0, be0, m0, v0, t);
  }
  __syncthreads();
  if (t < 64) {
    float acc = 0.f;
#pragma unroll 8
    for (int c = 0; c < 64; ++c) acc = fmaf(ch1[c], w1[t * 64 + c], acc);
    ch2[t] = bnrelu(acc, b1, g1, be1, m1, v1, t);
  }
  __syncthreads();
  if (t < 128) {
    float acc = 0.f;
#pragma unroll 8
    for (int c = 0; c < 64; ++c) acc = fmaf(ch2[c], w2[t * 64 + c], acc);
    ch3[t] = bnrelu(acc, b2, g2, be2, m2, v2, t);
  }
  __syncthreads();
  if (t < 128) {
    float acc = 0.f;
#pragma unroll 8
    for (int c = 0; c < 128; ++c) acc = fmaf(ch3[c], a[(3 + c) * 128 + t], acc);
    ceA[(size_t)bs * 128 + t] = acc;
  }
}

// ---------------------------------------------------------------------------
// Kernel 3 (mega v6): R10's verified v5 + ceA read hoisted to right after B1
// (depends only on bs; previously a naked ~500 cy L2 latency at F's head,
// now hidden under D+E).
// ---------------------------------------------------------------------------
__global__ __launch_bounds__(MEGA_THREADS) void mega_kernel(
    const float* __restrict__ points, const float* __restrict__ ceA,
    const float4* __restrict__ gq,
    const float* __restrict__ w0, const float* __restrict__ b0,
    const float* __restrict__ g0, const float* __restrict__ be0,
    const float* __restrict__ m0, const float* __restrict__ v0,
    const float* __restrict__ w1, const float* __restrict__ b1,
    const float* __restrict__ g1, const float* __restrict__ be1,
    const float* __restrict__ m1, const float* __restrict__ v1,
    const float* __restrict__ w2, const float* __restrict__ b2,
    const float* __restrict__ g2, const float* __restrict__ be2,
    const float* __restrict__ m2, const float* __restrict__ v2,
    const float* __restrict__ a, float* __restrict__ out1) {
  extern __shared__ float lds[];
  float* s_a  = lds + OFF_A;
  float* s_w1 = lds + OFF_W1;
  float* s_w2 = lds + OFF_W2;
  float* s_w0 = lds + OFF_W0;
  float* s_h1 = lds + OFF_H1;
  float* s_h2 = lds + OFF_H2;
  float* s_u  = lds + OFF_U;

  const int t = threadIdx.x;
  const int k = t & 31;             // C-phase neighbor row
  const int g16 = t >> 5;           // C-phase oc group 0..15
  const int kk = t & 15;            // D/E/F k base (rows kk, kk+16)
  const int gg = t >> 4;            // D/E/F oc group 0..31

  // ---- stage weights into LDS (once per block) ----
  {
    const float4* srcA = (const float4*)a;
    float4* dstA = (float4*)s_a;
    for (int i = t; i < 4192; i += MEGA_THREADS) dstA[i] = srcA[i];
    const float4* src1 = (const float4*)w1;
    float4* dst1 = (float4*)s_w1;
    for (int i = t; i < 1024; i += MEGA_THREADS) dst1[i] = src1[i];
    const float4* src2 = (const float4*)w2;
    float4* dst2 = (float4*)s_w2;
    for (int i = t; i < 2048; i += MEGA_THREADS) dst2[i] = src2[i];
    for (int i = t; i < 576; i += MEGA_THREADS) s_w0[i] = w0[i];
  }
  __syncthreads();

  const int bs0 = blockIdx.x * QPB;

  float4 gv = gq[(size_t)bs0 * NK + k];
  float pts[6];
  {
    int n = __float_as_int(gv.w);
    const float* pb = points + (size_t)(bs0 >> 10) * DIN * NPT + n;
#pragma unroll
    for (int c = 0; c < 6; ++c) pts[c] = pb[(size_t)c * NPT];
  }

  for (int q = 0; q < QPB; ++q) {
    const int bs = bs0 + q;
    const int b = bs >> 10;
    const int s = bs & 1023;

    const int qn = (q + 1 < QPB) ? (q + 1) : q;
    const int bsn = bs0 + qn;
    float4 gv_next = gq[(size_t)bsn * NK + k];

    // ---- C: layer 1, 9 -> 64 (k = t&31, oc = g16*4 + j) ----
    {
      float in0[9];
      in0[0] = gv.x; in0[1] = gv.y; in0[2] = gv.z;
#pragma unroll
      for (int c = 0; c < 6; ++c) in0[3 + c] = pts[c];
      int oc0 = g16 * 4;
      float acc[4];
#pragma unroll
      for (int j = 0; j < 4; ++j) {
        float a0 = 0.f;
#pragma unroll
        for (int c = 0; c < 9; ++c)
          a0 = fmaf(in0[c], s_w0[(oc0 + j) * 9 + c], a0);
        acc[j] = bnrelu(a0, b0, g0, be0, m0, v0, oc0 + j);
      }
      *(float4*)&s_h1[k * 68 + oc0] = make_float4(acc[0], acc[1], acc[2], acc[3]);
    }
    __syncthreads();  // B1

    // hoisted global reads: next query's point feats + THIS query's ceA row
    float pts_next[6];
    {
      int nn = __float_as_int(gv_next.w);
      const float* pbn = points + (size_t)(bsn >> 10) * DIN * NPT + nn;
#pragma unroll
      for (int c = 0; c < 6; ++c) pts_next[c] = pbn[(size_t)c * NPT];
    }
    float4 cv = *(const float4*)&ceA[(size_t)bs * 128 + gg * 4];

    // ---- D: layer 2, 64 -> 64; rows kk & kk+16, oc = gg*2 + j ----
    {
      int oc0 = gg * 2;
      float a0[2] = {0.f, 0.f}, a1[2] = {0.f, 0.f};
      const float4* row0 = (const float4*)&s_h1[kk * 68];
      const float4* row1 = (const float4*)&s_h1[(kk + 16) * 68];
#pragma unroll 4
      for (int c4 = 0; c4 < 16; ++c4) {
        float4 h0 = row0[c4];
        float4 h1 = row1[c4];
#pragma unroll
        for (int j = 0; j < 2; ++j) {
          float4 wv = *(const float4*)&s_w1[(oc0 + j) * 64 + c4 * 4];
          a0[j] = fmaf(h0.x, wv.x, a0[j]);
          a0[j] = fmaf(h0.y, wv.y, a0[j]);
          a0[j] = fmaf(h0.z, wv.z, a0[j]);
          a0[j] = fmaf(h0.w, wv.w, a0[j]);
          a1[j] = fmaf(h1.x, wv.x, a1[j]);
          a1[j] = fmaf(h1.y, wv.y, a1[j]);
          a1[j] = fmaf(h1.z, wv.z, a1[j]);
          a1[j] = fmaf(h1.w, wv.w, a1[j]);
        }
      }
#pragma unroll
      for (int j = 0; j < 2; ++j) {
        a0[j] = bnrelu(a0[j], b1, g1, be1, m1, v1, oc0 + j);
        a1[j] = bnrelu(a1[j], b1, g1, be1, m1, v1, oc0 + j);
      }
      s_h2[kk * 68 + oc0] = a0[0];
      s_h2[kk * 68 + oc0 + 1] = a0[1];
      s_h2[(kk + 16) * 68 + oc0] = a1[0];
      s_h2[(kk + 16) * 68 + oc0 + 1] = a1[1];
    }
    __syncthreads();  // B2

    // ---- E: layer 3, 64 -> 128; rows kk & kk+16, oc = gg*4 + j ----
    {
      int oc0 = gg * 4;
      float a0[4] = {0.f, 0.f, 0.f, 0.f}, a1[4] = {0.f, 0.f, 0.f, 0.f};
      const float4* row0 = (const float4*)&s_h2[kk * 68];
      const float4* row1 = (const float4*)&s_h2[(kk + 16) * 68];
#pragma unroll 4
      for (int c4 = 0; c4 < 16; ++c4) {
        float4 h0 = row0[c4];
        float4 h1 = row1[c4];
#pragma unroll
        for (int j = 0; j < 4; ++j) {
          float4 wv = *(const float4*)&s_w2[(oc0 + j) * 64 + c4 * 4];
          a0[j] = fmaf(h0.x, wv.x, a0[j]);
          a0[j] = fmaf(h0.y, wv.y, a0[j]);
          a0[j] = fmaf(h0.z, wv.z, a0[j]);
          a0[j] = fmaf(h0.w, wv.w, a0[j]);
          a1[j] = fmaf(h1.x, wv.x, a1[j]);
          a1[j] = fmaf(h1.y, wv.y, a1[j]);
          a1[j] = fmaf(h1.z, wv.z, a1[j]);
          a1[j] = fmaf(h1.w, wv.w, a1[j]);
        }
      }
#pragma unroll
      for (int j = 0; j < 4; ++j) {
        a0[j] = bnrelu(a0[j], b2, g2, be2, m2, v2, oc0 + j);
        a1[j] = bnrelu(a1[j], b2, g2, be2, m2, v2, oc0 + j);
      }
      *(float4*)&s_u[kk * 132 + oc0] = make_float4(a0[0], a0[1], a0[2], a0[3]);
      *(float4*)&s_u[(kk + 16) * 132 + oc0] =
          make_float4(a1[0], a1[1], a1[2], a1[3]);
      if (t < NK) {
        s_u[t * 132 + 128] = gv.x;
        s_u[t * 132 + 129] = gv.y;
        s_u[t * 132 + 130] = gv.z;
        s_u[t * 132 + 131] = 0.f;
      }
    }
    __syncthreads();  // B3

    // ---- F: attention; rows kk & kk+16, oc = gg*4 + j ----
    {
      int oc0 = gg * 4;
      float a0[4] = {0.f, 0.f, 0.f, 0.f}, a1[4] = {0.f, 0.f, 0.f, 0.f};
      const float4* urow0 = (const float4*)&s_u[kk * 132];
      const float4* urow1 = (const float4*)&s_u[(kk + 16) * 132];
      for (int r4 = 0; r4 < 33; ++r4) {
        float4 uv0 = urow0[r4];
        float4 uv1 = urow1[r4];
        int r = r4 * 4;
#pragma unroll
        for (int cc = 0; cc < 4; ++cc) {
          int rr = r + cc;
          int arow = (rr < 128) ? (rr + 3) : (rr - 128);  // rr==131 -> a[3]*0
          float uc0 = (cc == 0) ? uv0.x : (cc == 1) ? uv0.y : (cc == 2) ? uv0.z : uv0.w;
          float uc1 = (cc == 0) ? uv1.x : (cc == 1) ? uv1.y : (cc == 2) ? uv1.z : uv1.w;
          float4 av = *(const float4*)&s_a[arow * 128 + oc0];
          a0[0] = fmaf(uc0, av.x, a0[0]);
          a0[1] = fmaf(uc0, av.y, a0[1]);
          a0[2] = fmaf(uc0, av.z, a0[2]);
          a0[3] = fmaf(uc0, av.w, a0[3]);
          a1[0] = fmaf(uc1, av.x, a1[0]);
          a1[1] = fmaf(uc1, av.y, a1[1]);
          a1[2] = fmaf(uc1, av.z, a1[2]);
          a1[3] = fmaf(uc1, av.w, a1[3]);
        }
      }

      float4 h0v = *(const float4*)&s_u[kk * 132 + oc0];
      float4 h1v = *(const float4*)&s_u[(kk + 16) * 132 + oc0];
      float ce[4] = {cv.x, cv.y, cv.z, cv.w};
      float h0[4] = {h0v.x, h0v.y, h0v.z, h0v.w};
      float h1[4] = {h1v.x, h1v.y, h1v.z, h1v.w};

      float* outb = out1 + (size_t)b * 128 * NS + s;
#pragma unroll
      for (int j = 0; j < 4; ++j) {
        float e0 = ce[j] - a0[j];
        float e1 = ce[j] - a1[j];
        e0 = (e0 >= 0.f) ? e0 : 0.2f * e0;  // leaky relu alpha=0.2
        e1 = (e1 >= 0.f) ? e1 : 0.2f * e1;
        float mx = fmaxf(e0, e1);
#pragma unroll
        for (int off = 8; off > 0; off >>= 1)
          mx = fmaxf(mx, __shfl_xor(mx, off));   // stays in 16-lane group
        float p0 = expf(e0 - mx);
        float p1 = expf(e1 - mx);
        float num = p0 * h0[j] + p1 * h1[j];
        float den = p0 + p1;
#pragma unroll
        for (int off = 8; off > 0; off >>= 1) {
          num += __shfl_xor(num, off);
          den += __shfl_xor(den, off);
        }
        if (kk == 0) outb[(size_t)(oc0 + j) * NS] = num / den;
      }
    }
    // no trailing barrier needed (see R7 proof)

    gv = gv_next;
#pragma unroll
    for (int c = 0; c < 6; ++c) pts[c] = pts_next[c];
  }
}

// ---------------------------------------------------------------------------
extern "C" void kernel_launch(void* const* d_in, const int* in_sizes, int n_in,
                              void* d_out, int out_size, void* d_ws,
                              size_t ws_size, hipStream_t stream) {
  (void)in_sizes; (void)n_in; (void)out_size; (void)ws_size;
  const float* xyz = (const float*)d_in[0];
  const float* points = (const float*)d_in[1];
  const float* w0 = (const float*)d_in[2];
  const float* b0 = (const float*)d_in[3];
  const float* g0 = (const float*)d_in[4];
  const float* be0 = (const float*)d_in[5];
  const float* m0 = (const float*)d_in[6];
  const float* v0 = (const float*)d_in[7];
  const float* w1 = (const float*)d_in[8];
  const float* b1 = (const float*)d_in[9];
  const float* g1 = (const float*)d_in[10];
  const float* be1 = (const float*)d_in[11];
  const float* m1 = (const float*)d_in[12];
  const float* v1 = (const float*)d_in[13];
  const float* w2 = (const float*)d_in[14];
  const float* b2 = (const float*)d_in[15];
  const float* g2 = (const float*)d_in[16];
  const float* be2 = (const float*)d_in[17];
  const float* m2 = (const float*)d_in[18];
  const float* v2 = (const float*)d_in[19];
  const float* a = (const float*)d_in[20];

  float* out0 = (float*)d_out;                  // [B,3,S]
  float* out1 = out0 + (size_t)NB * 3 * NS;     // [B,128,S]

  int* fps = (int*)d_ws;                                        // 32 KB
  float* nxyz = (float*)((char*)d_ws + 32768);                  // 96 KB
  float* ceA = (float*)((char*)d_ws + 131072);                  // 4 MB
  float4* gq = (float4*)((char*)d_ws + 131072 + 4194304);       // 4 MB

  hipFuncSetAttribute(reinterpret_cast<const void*>(mega_kernel),
                      hipFuncAttributeMaxDynamicSharedMemorySize, SMEM_BYTES);

  fps_kernel<<<NB, 512, 0, stream>>>(xyz, fps, nxyz, out0);
  ballq_center_kernel<<<NB * NS, 256, 0, stream>>>(xyz, points, nxyz, fps,
      w0, b0, g0, be0, m0, v0, w1, b1, g1, be1, m1, v1,
      w2, b2, g2, be2, m2, v2, a, gq, ceA);
  mega_kernel<<<NB * NS / QPB, MEGA_THREADS, SMEM_BYTES, stream>>>(
      points, ceA, gq,
      w0, b0, g0, be0, m0, v0, w1, b1, g1, be1, m1, v1,
      w2, b2, g2, be2, m2, v2, a, out1);
}